// Round 5
// baseline (660.527 us; speedup 1.0000x reference)
//
#include <hip/hip_runtime.h>
#include <hip/hip_bf16.h>

typedef __attribute__((ext_vector_type(4))) float f32x4;
typedef __attribute__((ext_vector_type(8))) short bf16x8;
typedef __attribute__((ext_vector_type(4))) short s16x4;

#define NT 32  // K-tiles (K=1024, BK=32)

__device__ __forceinline__ short f2bfs(float f) {
  __hip_bfloat16 h = __float2bfloat16(f);   // RNE
  union { __hip_bfloat16 h; short s; } u; u.h = h;
  return u.s;
}
__device__ __forceinline__ float bf2fs(short s) {
  union { unsigned u; float f; } v; v.u = ((unsigned)(unsigned short)s) << 16;
  return v.f;
}

// async global->LDS, 16B/lane; LDS dest linear (wave base + lane*16)
__device__ __forceinline__ void gload16(void* l, const void* g) {
  __builtin_amdgcn_global_load_lds(
      (const __attribute__((address_space(1))) unsigned int*)g,
      (__attribute__((address_space(3))) unsigned int*)l, 16, 0, 0);
}

// counted-vmcnt wait + barrier (memory-clobbered so compiler can't reorder
// LDS/VMEM ops across; raw s_barrier keeps in-flight loads alive - T4)
#define WAITBAR(N)                                              \
  do {                                                          \
    asm volatile("s_waitcnt vmcnt(" #N ")" ::: "memory");       \
    __builtin_amdgcn_s_barrier();                               \
    asm volatile("" ::: "memory");                              \
  } while (0)

// Row maps for the A operand (radix-2 tree, verified in prior rounds).
// RM=0 identity; RM=1 L0 (XS in (b,t) layout): mul = ((R&63)<<9)|((R>>6)<<1)
// RM=2 seg-major: mul = ((R>>6)<<7)|(R&63)
template<int RM>
__device__ __forceinline__ int rmap(int R) {
  return (RM == 0) ? R
       : (RM == 1) ? (((R & 63) << 9) | ((R >> 6) << 1))
                   : (((R >> 6) << 7) | (R & 63));
}

// stage one K-tile (A 256x32 + B 256x32 bf16 = 32KB) into buf; 4 issues/thread
template<int RM>
__device__ __forceinline__ void stage_tile(
    char* buf, const short* __restrict__ A, const short* __restrict__ BT,
    int row0, int col0, int kt, int tid) {
  char* bufB = buf + 16384;
  #pragma unroll
  for (int i = 0; i < 2; ++i) {
    int G = i * 512 + tid;
    int r = G >> 2, g = G & 3;
    int gs = g ^ ((r >> 1) & 3);
    gload16(buf + (size_t)G * 16,
            A + (size_t)rmap<RM>(row0 + r) * 1024 + kt * 32 + gs * 8);
  }
  #pragma unroll
  for (int i = 0; i < 2; ++i) {
    int G = i * 512 + tid;
    int r = G >> 2, g = G & 3;
    int gs = g ^ ((r >> 1) & 3);
    gload16(bufB + (size_t)G * 16,
            BT + (size_t)(col0 + r) * 1024 + kt * 32 + gs * 8);
  }
}

// ---------------------------------------------------------------------------
// 256x256 tile, 8 waves (2Mx4N), per-wave 128x64 = 8x4 frags of 16x16x32.
// Depth-3 pipeline over 4 LDS buffers; one barrier + counted vmcnt per K-tile.
// ---------------------------------------------------------------------------
template<int RM>
__device__ __forceinline__ void pass256(
    char* lds, f32x4 (&acc)[8][4],
    const short* __restrict__ A, const short* __restrict__ BT,
    int row0, int col0, int tid, int wave, int lane) {
  const int wm = wave >> 2, wn = wave & 3;
  const int l16 = lane & 15, kg = lane >> 4;

  #pragma unroll
  for (int p = 0; p < 3; ++p)
    stage_tile<RM>(lds + p * 32768, A, BT, row0, col0, p, tid);

  for (int t = 0; t < NT; ++t) {
    if (t < NT - 2)       WAITBAR(8);   // tiles t+1,t+2 stay in flight
    else if (t == NT - 2) WAITBAR(4);
    else                  WAITBAR(0);
    if (t + 3 < NT)
      stage_tile<RM>(lds + ((t + 3) & 3) * 32768, A, BT, row0, col0, t + 3, tid);

    const char* bufA = lds + (t & 3) * 32768;
    const char* bufB = bufA + 16384;
    bf16x8 bfr[4], af[8];
    #pragma unroll
    for (int n = 0; n < 4; ++n) {
      int c = wn * 64 + n * 16 + l16;
      int g = kg ^ ((c >> 1) & 3);
      bfr[n] = *(const bf16x8*)(bufB + (c * 4 + g) * 16);
    }
    #pragma unroll
    for (int m = 0; m < 8; ++m) {
      int rr = wm * 128 + m * 16 + l16;
      int g = kg ^ ((rr >> 1) & 3);
      af[m] = *(const bf16x8*)(bufA + (rr * 4 + g) * 16);
    }
    __builtin_amdgcn_s_setprio(1);
    #pragma unroll
    for (int m = 0; m < 8; ++m)
      #pragma unroll
      for (int n = 0; n < 4; ++n)
        acc[m][n] = __builtin_amdgcn_mfma_f32_16x16x32_bf16(af[m], bfr[n], acc[m][n], 0, 0, 0);
    __builtin_amdgcn_s_setprio(0);
  }
}

// epilogue: C/D layout col=lane&15, row=(lane>>4)*4+reg  [HW-verified]
// ADD: 0 none; 1 L0 add (XS map +1); 2 seg add (+64). OUT: 0 bf16; 2 fp32
template<int ADD, int OUT>
__device__ __forceinline__ void epi256(
    f32x4 (&acc)[8][4], void* __restrict__ Cp, const short* __restrict__ AddP,
    int row0, int col0, int M, int wave, int lane) {
  const int wm = wave >> 2, wn = wave & 3;
  const int l16 = lane & 15;
  #pragma unroll
  for (int m = 0; m < 8; ++m) {
    #pragma unroll
    for (int n = 0; n < 4; ++n) {
      const int grow0 = row0 + wm * 128 + m * 16 + ((lane >> 4) << 2);
      const int gcol  = col0 + wn * 64 + n * 16 + l16;
      #pragma unroll
      for (int r = 0; r < 4; ++r) {
        const int R = grow0 + r;
        if (R < M) {
          float val = acc[m][n][r];
          if (ADD == 1) {
            int ar = (((R & 63) << 9) | ((R >> 6) << 1)) + 1;
            val += bf2fs(AddP[(size_t)ar * 1024 + gcol]);
          } else if (ADD == 2) {
            int ar = (((R >> 6) << 7) | (R & 63)) + 64;
            val += bf2fs(AddP[(size_t)ar * 1024 + gcol]);
          }
          if (OUT == 0) ((short*)Cp)[(size_t)R * 1024 + gcol] = f2bfs(val);
          else          ((float*)Cp)[(size_t)R * 1024 + gcol] = val;
        }
      }
    }
  }
}

// ---------------- generic launch: sq jobs first (16 blocks/form), then main -
template<int RM, int ADD, int OUT>
__global__ __launch_bounds__(512) void k_g(
    const short* __restrict__ A, const short* __restrict__ BT,
    void* __restrict__ Cp, const short* __restrict__ AddP, int M, int nSq,
    const short* __restrict__ sqA0, const short* __restrict__ sqB0, short* __restrict__ sqC0,
    const short* __restrict__ sqA1, const short* __restrict__ sqB1, short* __restrict__ sqC1) {
  __shared__ __align__(16) char lds[131072];
  f32x4 acc[8][4] = {};
  const int tid = threadIdx.x, wave = tid >> 6, lane = tid & 63;
  const int b = blockIdx.x;
  if (b < nSq) {
    int f = b >> 4, q = b & 15;
    int row0 = (q >> 2) * 256, col0 = (q & 3) * 256;
    const short* sa = f ? sqA1 : sqA0;
    const short* sb = f ? sqB1 : sqB0;
    short* sc = f ? sqC1 : sqC0;
    pass256<0>(lds, acc, sa, sb, row0, col0, tid, wave, lane);
    epi256<0, 0>(acc, sc, nullptr, row0, col0, 1024, wave, lane);
  } else {
    int c = b - nSq;
    int row0 = (c >> 2) * 256, col0 = (c & 3) * 256;   // col-fastest: L2 A-reuse
    pass256<RM>(lds, acc, A, BT, row0, col0, tid, wave, lane);
    epi256<ADD, OUT>(acc, Cp, AddP, row0, col0, M, wave, lane);
  }
}

// ---------------- prep: WT, UT (transposed bf16), Ub, XB (bf16 casts) -------
__global__ __launch_bounds__(256) void k_prep(
    const float* __restrict__ W, const float* __restrict__ Uf,
    const float* __restrict__ X,
    short* __restrict__ WT, short* __restrict__ UT,
    short* __restrict__ Ub, short* __restrict__ XB) {
  __shared__ float tf[32][36];
  int b = blockIdx.x, t = threadIdx.x;
  if (b < 2048) {
    const float* src = (b < 1024) ? W : Uf;
    short* dst = (b < 1024) ? WT : UT;
    int bb = b & 1023;
    int i0 = (bb >> 5) * 32, j0 = (bb & 31) * 32;
    int r = t >> 3, c = (t & 7) * 4;
    *(f32x4*)&tf[r][c] = *(const f32x4*)(src + (size_t)(i0 + r) * 1024 + j0 + c);
    __syncthreads();
    s16x4 o;
    o.x = f2bfs(tf[c + 0][r]); o.y = f2bfs(tf[c + 1][r]);
    o.z = f2bfs(tf[c + 2][r]); o.w = f2bfs(tf[c + 3][r]);
    *(s16x4*)(dst + (size_t)(j0 + r) * 1024 + i0 + c) = o;
  } else if (b < 2560) {
    int q = b - 2048;
    size_t base = (size_t)q * 2048 + (size_t)t * 8;
    f32x4 a = *(const f32x4*)(Uf + base);
    f32x4 c2 = *(const f32x4*)(Uf + base + 4);
    bf16x8 o;
    o[0] = f2bfs(a.x);  o[1] = f2bfs(a.y);  o[2] = f2bfs(a.z);  o[3] = f2bfs(a.w);
    o[4] = f2bfs(c2.x); o[5] = f2bfs(c2.y); o[6] = f2bfs(c2.z); o[7] = f2bfs(c2.w);
    *(bf16x8*)(Ub + base) = o;
  } else {
    int q = b - 2560;
    size_t base = ((size_t)q * 256 + t) * 32;
    #pragma unroll
    for (int i = 0; i < 4; ++i) {
      f32x4 a = *(const f32x4*)(X + base + i * 8);
      f32x4 c2 = *(const f32x4*)(X + base + i * 8 + 4);
      bf16x8 o;
      o[0] = f2bfs(a.x);  o[1] = f2bfs(a.y);  o[2] = f2bfs(a.z);  o[3] = f2bfs(a.w);
      o[4] = f2bfs(c2.x); o[5] = f2bfs(c2.y); o[6] = f2bfs(c2.z); o[7] = f2bfs(c2.w);
      *(bf16x8*)(XB + base + i * 8) = o;
    }
  }
}

extern "C" void kernel_launch(void* const* d_in, const int* in_sizes, int n_in,
                              void* d_out, int out_size, void* d_ws, size_t ws_size,
                              hipStream_t stream) {
  const float* X = (const float*)d_in[0];   // [64,512,1024] fp32
  const float* W = (const float*)d_in[1];   // [1024,1024] fp32
  const float* U = (const float*)d_in[2];   // [1024,1024] fp32
  float* out = (float*)d_out;               // [64,1024] fp32

  char* ws = (char*)d_ws;
  short* RA = (short*)ws;                        // XS, then F2,F4,F6,F8
  short* RB = (short*)(ws + ((size_t)64 << 20)); // XB, then F1,F3,F5,F7
  char* pb  = ws + ((size_t)128 << 20);          // bf16 power slots (2MB each)
  const size_t SL = (size_t)2 << 20;
  short* p0  = (short*)(pb + 0 * SL);   // U (bf16)
  short* pt0 = (short*)(pb + 1 * SL);   // U^T, later U^8T, U^64T
  short* pA  = (short*)(pb + 2 * SL);   // U^2, U^8, U^32, U^128
  short* ptA = (short*)(pb + 3 * SL);   // U^2T, U^16T, U^128T
  short* pB  = (short*)(pb + 4 * SL);   // WT first, then U^4, U^16, U^64
  short* ptB = (short*)(pb + 5 * SL);   // U^4T, U^32T, U^256T
  short* WT  = pB;                      // WT dead before pB first written (L0)

  short* XS = RA;
  short* XB = RB;

  k_prep<<<6656, 256, 0, stream>>>(W, U, X, WT, pt0, p0, XB);

  // XS = XB @ WT^T (M=32768) + sq: U^2 (pA), U^2T (ptA)
  k_g<0, 0, 0><<<544, 512, 0, stream>>>(XB, WT, XS, nullptr, 32768, 32,
                                        p0, pt0, pA, pt0, p0, ptA);
  // L0: F1 = XS[even]*U + XS[odd] (M=16384) + sq: U^4 (pB), U^4T (ptB)
  k_g<1, 1, 0><<<288, 512, 0, stream>>>(XS, pt0, RB, XS, 16384, 32,
                                        pA, ptA, pB, ptA, pA, ptB);
  // L1 (M=8192): uses U^2T; builds U^8 -> (pA, pt0)
  k_g<2, 2, 0><<<160, 512, 0, stream>>>(RB, ptA, RA, RB, 8192, 32,
                                        pB, ptB, pA, ptB, pB, pt0);
  // L2 (M=4096): uses U^4T; builds U^16 -> (pB, ptA)
  k_g<2, 2, 0><<<96, 512, 0, stream>>>(RA, ptB, RB, RA, 4096, 32,
                                       pA, pt0, pB, pt0, pA, ptA);
  // L3 (M=2048): uses U^8T; builds U^32 -> (pA, ptB)
  k_g<2, 2, 0><<<64, 512, 0, stream>>>(RB, pt0, RA, RB, 2048, 32,
                                       pB, ptA, pA, ptA, pB, ptB);
  // L4 (M=1024): uses U^16T; builds U^64 -> (pB, pt0)
  k_g<2, 2, 0><<<48, 512, 0, stream>>>(RA, ptA, RB, RA, 1024, 32,
                                       pA, ptB, pB, ptB, pA, pt0);
  // L5 (M=512): uses U^32T; builds U^128 -> (pA, ptA)
  k_g<2, 2, 0><<<40, 512, 0, stream>>>(RB, ptB, RA, RB, 512, 32,
                                       pB, pt0, pA, pt0, pB, ptA);
  // L6 (M=256): uses U^64T; builds U^256T only -> ptB
  k_g<2, 2, 0><<<20, 512, 0, stream>>>(RA, pt0, RB, RA, 256, 16,
                                       ptA, pA, ptB, nullptr, nullptr, nullptr);
  // L7 (M=128): uses U^128T
  k_g<2, 2, 0><<<4, 512, 0, stream>>>(RB, ptA, RA, RB, 128, 0,
                                      nullptr, nullptr, nullptr, nullptr, nullptr, nullptr);
  // L8 (M=64): uses U^256T, writes fp32 d_out
  k_g<2, 2, 2><<<4, 512, 0, stream>>>(RA, ptB, out, RA, 64, 0,
                                      nullptr, nullptr, nullptr, nullptr, nullptr, nullptr);
}

// Round 7
// 422.001 us; speedup vs baseline: 1.5652x; 1.5652x over previous
//
#include <hip/hip_runtime.h>
#include <hip/hip_bf16.h>

typedef __attribute__((ext_vector_type(4))) float f32x4;
typedef __attribute__((ext_vector_type(8))) short bf16x8;
typedef __attribute__((ext_vector_type(4))) short s16x4;

#define SLOT (1024 * 1024)   // elements per 2MB bf16 power slot

__device__ __forceinline__ short f2bfs(float f) {
  __hip_bfloat16 h = __float2bfloat16(f);   // RNE
  union { __hip_bfloat16 h; short s; } u; u.h = h;
  return u.s;
}
__device__ __forceinline__ float bf2fs(short s) {
  union { unsigned u; float f; } v; v.u = ((unsigned)(unsigned short)s) << 16;
  return v.f;
}

// async global->LDS, 16B/lane; LDS dest linear (wave base + lane*16)
__device__ __forceinline__ void gload16(void* l, const void* g) {
  __builtin_amdgcn_global_load_lds(
      (const __attribute__((address_space(1))) unsigned int*)g,
      (__attribute__((address_space(3))) unsigned int*)l, 16, 0, 0);
}

// RM=0 identity; RM=1 chunk-pair (F0 b-major, 256 segs): mul=((R&63)<<8)|((R>>6)<<1)
// RM=2 seg-major radix-2: mul=((R>>6)<<7)|(R&63)
template<int RM>
__device__ __forceinline__ int rmap(int R) {
  return (RM == 0) ? R
       : (RM == 1) ? (((R & 63) << 8) | ((R >> 6) << 1))
                   : (((R >> 6) << 7) | (R & 63));
}

// ---------------------------------------------------------------------------
// 128x128 tile, 4 waves (2x2), 16x16x32 MFMA. 2-phase double-buffered LDS
// (T3 minimum recipe): stage(t+1) issued BEFORE compute(t); ONE barrier/K-step
// (__syncthreads drains vmcnt -> next tile landed + LDS safe to restage).
// Staging: global_load_lds w=16, pre-swizzled source; ds_read same XOR.
// ---------------------------------------------------------------------------
template<int RM>
__device__ __forceinline__ void gemm128(
    char* lds, f32x4 (&acc)[4][4],
    const short* __restrict__ A, int lda,
    const short* __restrict__ BT, int ldb,
    int row0, int col0, int nkt, int tid, int wave, int lane) {
  const int wm = wave >> 1, wn = wave & 1;
  const int l16 = lane & 15, kg = lane >> 4;
  const int r0 = tid >> 2, g0 = tid & 3;
  const int gs0 = g0 ^ ((r0 >> 1) & 3);
  const int r1 = r0 + 64;
  const int gs1 = g0 ^ ((r1 >> 1) & 3);
  const short* a0 = A + (size_t)rmap<RM>(row0 + r0) * lda + gs0 * 8;
  const short* a1 = A + (size_t)rmap<RM>(row0 + r1) * lda + gs1 * 8;
  const short* b0 = BT + (size_t)(col0 + r0) * ldb + gs0 * 8;
  const short* b1 = BT + (size_t)(col0 + r1) * ldb + gs1 * 8;
  const int dA0 = tid * 16, dA1 = dA0 + 4096;
  const int dB0 = 8192 + tid * 16, dB1 = dB0 + 4096;

  int offA[4], offB[4];
  #pragma unroll
  for (int m = 0; m < 4; ++m) {
    int row = wm * 64 + m * 16 + l16;
    offA[m] = (row * 4 + (kg ^ ((row >> 1) & 3))) * 16;
  }
  #pragma unroll
  for (int n = 0; n < 4; ++n) {
    int c = wn * 64 + n * 16 + l16;
    offB[n] = 8192 + (c * 4 + (kg ^ ((c >> 1) & 3))) * 16;
  }

  // prologue: stage tile 0 into buf0
  gload16(lds + dA0, a0); gload16(lds + dA1, a1);
  gload16(lds + dB0, b0); gload16(lds + dB1, b1);
  __syncthreads();

  for (int t = 0; t < nkt; ++t) {
    char* cur = lds + (t & 1) * 16384;
    char* nxt = lds + ((t + 1) & 1) * 16384;
    if (t + 1 < nkt) {                       // issue next-tile loads FIRST
      const int ko = (t + 1) * 32;
      gload16(nxt + dA0, a0 + ko); gload16(nxt + dA1, a1 + ko);
      gload16(nxt + dB0, b0 + ko); gload16(nxt + dB1, b1 + ko);
    }
    bf16x8 af[4], bfr[4];
    #pragma unroll
    for (int m = 0; m < 4; ++m) af[m] = *(const bf16x8*)(cur + offA[m]);
    #pragma unroll
    for (int n = 0; n < 4; ++n) bfr[n] = *(const bf16x8*)(cur + offB[n]);
    #pragma unroll
    for (int m = 0; m < 4; ++m)
      #pragma unroll
      for (int n = 0; n < 4; ++n)
        acc[m][n] = __builtin_amdgcn_mfma_f32_16x16x32_bf16(af[m], bfr[n], acc[m][n], 0, 0, 0);
    __syncthreads();   // drains vmcnt(0) (next tile staged) + protects LDS
  }
}

// epilogue: C/D layout col=lane&15, row=(lane>>4)*4+reg  [HW-verified]
// ADD: 0 none; 1 chunk-pair add (mul+1); 2 seg add (+64). OUT: 0 bf16; 1 fp32
template<int ADD, int OUT>
__device__ __forceinline__ void epi128(
    f32x4 (&acc)[4][4], void* __restrict__ Cp, int ldc,
    const short* __restrict__ AddP,
    int row0, int col0, int M, int wave, int lane) {
  const int wm = wave >> 1, wn = wave & 1;
  const int l16 = lane & 15;
  #pragma unroll
  for (int m = 0; m < 4; ++m) {
    #pragma unroll
    for (int n = 0; n < 4; ++n) {
      const int grow0 = row0 + wm * 64 + m * 16 + ((lane >> 4) << 2);
      const int gcol  = col0 + wn * 64 + n * 16 + l16;
      #pragma unroll
      for (int r = 0; r < 4; ++r) {
        const int R = grow0 + r;
        if (R < M) {
          float val = acc[m][n][r];
          if (ADD == 1) {
            int ar = (((R & 63) << 8) | ((R >> 6) << 1)) + 1;
            val += bf2fs(AddP[(size_t)ar * 1024 + gcol]);
          } else if (ADD == 2) {
            int ar = (((R >> 6) << 7) | (R & 63)) + 64;
            val += bf2fs(AddP[(size_t)ar * 1024 + gcol]);
          }
          if (OUT == 0) ((short*)Cp)[(size_t)R * ldc + gcol] = f2bfs(val);
          else          ((float*)Cp)[(size_t)R * ldc + gcol] = val;
        }
      }
    }
  }
}

// one 1024x1024 power-product unit: C = A * BT^T (bf16)
__device__ __forceinline__ void run_unit(char* lds,
    const short* A, const short* BT, short* C,
    int tile, int tid, int wave, int lane) {
  f32x4 acc[4][4] = {};
  int row0 = (tile >> 3) * 128, col0 = (tile & 7) * 128;
  gemm128<0>(lds, acc, A, 1024, BT, 1024, row0, col0, 32, tid, wave, lane);
  epi128<0, 0>(acc, C, 1024, nullptr, row0, col0, 1024, wave, lane);
}

// Slots: 0 UT, 1 U2T, 2 U4T, 3 U8T, 4 U16T, 5 U32T, 6 U64T, 7 U128T, 8 U256T,
//        9 Ub, 10 U2, 11 U4, 12 U8, 13 U16, 14 U32, 15 U64, 16 U128, 17 Wb

// ---------------- prep: transposes + bf16 casts ----------------
__global__ __launch_bounds__(256) void k_prep(
    const float* __restrict__ W, const float* __restrict__ Uf,
    const float* __restrict__ X,
    short* __restrict__ BTcat, short* __restrict__ slab, short* __restrict__ XB) {
  __shared__ float tf[32][36];
  int b = blockIdx.x, t = threadIdx.x;
  if (b < 2048) {
    const float* src = (b < 1024) ? W : Uf;
    int bb = b & 1023;
    int i0 = (bb >> 5) * 32, j0 = (bb & 31) * 32;
    int r = t >> 3, c = (t & 7) * 4;
    *(f32x4*)&tf[r][c] = *(const f32x4*)(src + (size_t)(i0 + r) * 1024 + j0 + c);
    __syncthreads();
    s16x4 o;
    o.x = f2bfs(tf[c + 0][r]); o.y = f2bfs(tf[c + 1][r]);
    o.z = f2bfs(tf[c + 2][r]); o.w = f2bfs(tf[c + 3][r]);
    if (b < 1024)  // W^T -> BTcat col-block 1 (K idx 1024..2047)
      *(s16x4*)(BTcat + (size_t)(j0 + r) * 2048 + 1024 + i0 + c) = o;
    else           // U^T -> slot 0
      *(s16x4*)(slab + (size_t)(j0 + r) * 1024 + i0 + c) = o;
  } else if (b < 3072) {
    int q = b - 2048;   // first 512 = U cast (slot 9), next 512 = W cast (slot 17)
    const float* src = (q < 512) ? Uf : W;
    short* dst = slab + (size_t)((q < 512) ? 9 : 17) * SLOT;
    int qq = q & 511;
    size_t base = (size_t)qq * 2048 + (size_t)t * 8;
    f32x4 a = *(const f32x4*)(src + base);
    f32x4 c2 = *(const f32x4*)(src + base + 4);
    bf16x8 o;
    o[0] = f2bfs(a.x);  o[1] = f2bfs(a.y);  o[2] = f2bfs(a.z);  o[3] = f2bfs(a.w);
    o[4] = f2bfs(c2.x); o[5] = f2bfs(c2.y); o[6] = f2bfs(c2.z); o[7] = f2bfs(c2.w);
    *(bf16x8*)(dst + base) = o;
  } else {
    int q = b - 3072;   // 0..4095: X cast (33.5M elems)
    size_t base = ((size_t)q * 256 + t) * 32;
    #pragma unroll
    for (int i = 0; i < 4; ++i) {
      f32x4 a = *(const f32x4*)(X + base + i * 8);
      f32x4 c2 = *(const f32x4*)(X + base + i * 8 + 4);
      bf16x8 o;
      o[0] = f2bfs(a.x);  o[1] = f2bfs(a.y);  o[2] = f2bfs(a.z);  o[3] = f2bfs(a.w);
      o[4] = f2bfs(c2.x); o[5] = f2bfs(c2.y); o[6] = f2bfs(c2.z); o[7] = f2bfs(c2.w);
      *(bf16x8*)(XB + base + i * 8) = o;
    }
  }
}

// ---------------- k_pre: U2T, U2, TW1T=(WU)^T -> BTcat block 0 --------------
__global__ __launch_bounds__(256) void k_pre(short* slab, short* BTcat) {
  __shared__ __align__(16) char lds[32768];
  int tid = threadIdx.x, wave = tid >> 6, lane = tid & 63;
  int b = blockIdx.x, u = b >> 6, q = b & 63;
  if (u == 0)       // U2T = g(UT, Ub) = U^T U^T = (U^2)^T
    run_unit(lds, slab, slab + (size_t)9 * SLOT, slab + (size_t)1 * SLOT,
             q, tid, wave, lane);
  else if (u == 1)  // U2 = g(Ub, UT) = U U
    run_unit(lds, slab + (size_t)9 * SLOT, slab, slab + (size_t)10 * SLOT,
             q, tid, wave, lane);
  else {  // TW1T = g(UT, Wb) = U^T W^T = (WU)^T -> BTcat cols [0,1024), ldc 2048
    f32x4 acc[4][4] = {};
    int row0 = (q >> 3) * 128, col0 = (q & 7) * 128;
    gemm128<0>(lds, acc, slab, 1024, slab + (size_t)17 * SLOT, 1024,
               row0, col0, 32, tid, wave, lane);
    epi128<0, 0>(acc, BTcat, 2048, nullptr, row0, col0, 1024, wave, lane);
  }
}

// ---------------- k_big: F0[16384][1024] = XB[16384x2048] * BTcat^T ---------
// F0 row R=b*256+s: x_{b,2s}*(WU) + x_{b,2s+1}*W  (XB viewed lda=2048)
// + fused squares U4T=g(U2T,U2), U4=g(U2,U2T)
__global__ __launch_bounds__(256) void k_big(
    const short* __restrict__ XB, const short* __restrict__ BTcat,
    short* __restrict__ FA, short* slab) {
  __shared__ __align__(16) char lds[32768];
  int tid = threadIdx.x, wave = tid >> 6, lane = tid & 63;
  int b = blockIdx.x;
  if (b < 1024) {
    f32x4 acc[4][4] = {};
    int row0 = (b >> 3) * 128, col0 = (b & 7) * 128;   // col-fastest: L2 A-reuse
    gemm128<0>(lds, acc, XB, 2048, BTcat, 2048, row0, col0, 64, tid, wave, lane);
    epi128<0, 0>(acc, FA, 1024, nullptr, row0, col0, 16384, wave, lane);
  } else {
    int q = b - 1024, tl = q & 63;
    if (q < 64)
      run_unit(lds, slab + (size_t)1 * SLOT, slab + (size_t)10 * SLOT,
               slab + (size_t)2 * SLOT, tl, tid, wave, lane);   // U4T
    else
      run_unit(lds, slab + (size_t)10 * SLOT, slab + (size_t)1 * SLOT,
               slab + (size_t)11 * SLOT, tl, tid, wave, lane);  // U4
  }
}

// ---------------- tail level: combine (blocks < nComb) + 0-2 square units ---
template<int RM, int OUT>
__global__ __launch_bounds__(256) void k_lvl(
    const short* __restrict__ Fin, const short* __restrict__ PT,
    void* __restrict__ Fout, int M, int nComb,
    const short* __restrict__ sA0, const short* __restrict__ sB0, short* __restrict__ sC0,
    const short* __restrict__ sA1, const short* __restrict__ sB1, short* __restrict__ sC1) {
  __shared__ __align__(16) char lds[32768];
  int tid = threadIdx.x, wave = tid >> 6, lane = tid & 63;
  int b = blockIdx.x;
  if (b < nComb) {
    f32x4 acc[4][4] = {};
    int row0 = (b >> 3) * 128, col0 = (b & 7) * 128;
    gemm128<RM>(lds, acc, Fin, 1024, PT, 1024, row0, col0, 32, tid, wave, lane);
    epi128<RM, OUT>(acc, Fout, (OUT == 1) ? 1024 : 1024, Fin, row0, col0, M, wave, lane);
  } else {
    int q = b - nComb;
    const short* sa = (q < 64) ? sA0 : sA1;
    const short* sb = (q < 64) ? sB0 : sB1;
    short* sc = (q < 64) ? sC0 : sC1;
    run_unit(lds, sa, sb, sc, q & 63, tid, wave, lane);
  }
}

extern "C" void kernel_launch(void* const* d_in, const int* in_sizes, int n_in,
                              void* d_out, int out_size, void* d_ws, size_t ws_size,
                              hipStream_t stream) {
  const float* X = (const float*)d_in[0];   // [64,512,1024] fp32
  const float* W = (const float*)d_in[1];   // [1024,1024] fp32
  const float* U = (const float*)d_in[2];   // [1024,1024] fp32
  float* outp = (float*)d_out;              // [64,1024] fp32

  char* ws = (char*)d_ws;
  short* XB    = (short*)ws;                          // [0,64MB) bf16 X (lda-2048 view)
  short* FB    = (short*)ws;                          // aliases XB (dead after k_big)
  short* BTcat = (short*)(ws + ((size_t)64 << 20));   // [64,68) bf16 [1024][2048]
  short* slab  = (short*)(ws + ((size_t)68 << 20));   // [68,104) 18 x 2MB slots
  short* FA    = (short*)(ws + ((size_t)104 << 20));  // [104,136) bf16 [16384][1024]
  auto sl = [&](int i) { return slab + (size_t)i * SLOT; };

  k_prep<<<7168, 256, 0, stream>>>(W, U, X, BTcat, slab, XB);
  k_pre<<<192, 256, 0, stream>>>(slab, BTcat);
  k_big<<<1152, 256, 0, stream>>>(XB, BTcat, FA, slab);

  // ph0: M=8192 (RM1, U2T); sq U8T=g(U4T,U4), U8=g(U4,U4T)
  k_lvl<1, 0><<<640, 256, 0, stream>>>(FA, sl(1), FB, 8192, 512,
                                       sl(2), sl(11), sl(3), sl(11), sl(2), sl(12));
  // ph1: M=4096 (RM2, U4T); sq U16T=g(U8T,U8), U16=g(U8,U8T)
  k_lvl<2, 0><<<384, 256, 0, stream>>>(FB, sl(2), FA, 4096, 256,
                                       sl(3), sl(12), sl(4), sl(12), sl(3), sl(13));
  // ph2: M=2048 (U8T); sq U32T, U32
  k_lvl<2, 0><<<256, 256, 0, stream>>>(FA, sl(3), FB, 2048, 128,
                                       sl(4), sl(13), sl(5), sl(13), sl(4), sl(14));
  // ph3: M=1024 (U16T); sq U64T, U64
  k_lvl<2, 0><<<192, 256, 0, stream>>>(FB, sl(4), FA, 1024, 64,
                                       sl(5), sl(14), sl(6), sl(14), sl(5), sl(15));
  // ph4: M=512 (U32T); sq U128T, U128
  k_lvl<2, 0><<<160, 256, 0, stream>>>(FA, sl(5), FB, 512, 32,
                                       sl(6), sl(15), sl(7), sl(15), sl(6), sl(16));
  // ph5: M=256 (U64T); sq U256T only
  k_lvl<2, 0><<<80, 256, 0, stream>>>(FB, sl(6), FA, 256, 16,
                                      sl(7), sl(16), sl(8), nullptr, nullptr, nullptr);
  // ph6: M=128 (U128T)
  k_lvl<2, 0><<<8, 256, 0, stream>>>(FA, sl(7), FB, 128, 8,
                                     nullptr, nullptr, nullptr, nullptr, nullptr, nullptr);
  // ph7: M=64 (U256T), fp32 -> d_out
  k_lvl<2, 1><<<8, 256, 0, stream>>>(FB, sl(8), outp, 64, 8,
                                     nullptr, nullptr, nullptr, nullptr, nullptr, nullptr);
}

// Round 8
// 387.570 us; speedup vs baseline: 1.7043x; 1.0888x over previous
//
#include <hip/hip_runtime.h>
#include <hip/hip_bf16.h>

typedef __attribute__((ext_vector_type(4))) float f32x4;
typedef __attribute__((ext_vector_type(8))) short bf16x8;
typedef __attribute__((ext_vector_type(4))) short s16x4;

#define SLOT (1024 * 1024)   // elements per 2MB bf16 power slot

__device__ __forceinline__ short f2bfs(float f) {
  __hip_bfloat16 h = __float2bfloat16(f);   // RNE
  union { __hip_bfloat16 h; short s; } u; u.h = h;
  return u.s;
}
__device__ __forceinline__ float bf2fs(short s) {
  union { unsigned u; float f; } v; v.u = ((unsigned)(unsigned short)s) << 16;
  return v.f;
}

// async global->LDS, 16B/lane; LDS dest linear (wave base + lane*16)
__device__ __forceinline__ void gload16(void* l, const void* g) {
  __builtin_amdgcn_global_load_lds(
      (const __attribute__((address_space(1))) unsigned int*)g,
      (__attribute__((address_space(3))) unsigned int*)l, 16, 0, 0);
}

// RM=0 identity; RM=1 chunk-pair (F0 b-major, 256 segs): mul=((R&63)<<8)|((R>>6)<<1)
// RM=2 seg-major radix-2: mul=((R>>6)<<7)|(R&63)
template<int RM>
__device__ __forceinline__ int rmap(int R) {
  return (RM == 0) ? R
       : (RM == 1) ? (((R & 63) << 8) | ((R >> 6) << 1))
                   : (((R >> 6) << 7) | (R & 63));
}

// ---------------------------------------------------------------------------
// Shared per-thread addressing for 128x128 tile staging (A 128x32 + B 128x32).
// Swizzle: granule g at row r stored at g ^ ((r>>1)&3); involution on read.
// ---------------------------------------------------------------------------
struct TileAddr {
  const short *a0, *a1, *b0, *b1;
  int dA0, dA1, dB0, dB1;
  int offA[4], offB[4];
};
template<int RM>
__device__ __forceinline__ TileAddr mk_addr(
    const short* A, int lda, const short* BT, int ldb,
    int row0, int col0, int tid, int wave, int lane) {
  TileAddr t;
  const int wm = wave >> 1, wn = wave & 1;
  const int l16 = lane & 15, kg = lane >> 4;
  const int r0 = tid >> 2, g0 = tid & 3;
  const int gs0 = g0 ^ ((r0 >> 1) & 3);
  const int r1 = r0 + 64;
  const int gs1 = g0 ^ ((r1 >> 1) & 3);
  t.a0 = A + (size_t)rmap<RM>(row0 + r0) * lda + gs0 * 8;
  t.a1 = A + (size_t)rmap<RM>(row0 + r1) * lda + gs1 * 8;
  t.b0 = BT + (size_t)(col0 + r0) * ldb + gs0 * 8;
  t.b1 = BT + (size_t)(col0 + r1) * ldb + gs1 * 8;
  t.dA0 = tid * 16; t.dA1 = t.dA0 + 4096;
  t.dB0 = 8192 + tid * 16; t.dB1 = t.dB0 + 4096;
  #pragma unroll
  for (int m = 0; m < 4; ++m) {
    int row = wm * 64 + m * 16 + l16;
    t.offA[m] = (row * 4 + (kg ^ ((row >> 1) & 3))) * 16;
  }
  #pragma unroll
  for (int n = 0; n < 4; ++n) {
    int c = wn * 64 + n * 16 + l16;
    t.offB[n] = 8192 + (c * 4 + (kg ^ ((c >> 1) & 3))) * 16;
  }
  return t;
}
__device__ __forceinline__ void stage_to(const TileAddr& ta, char* buf, int ko) {
  gload16(buf + ta.dA0, ta.a0 + ko); gload16(buf + ta.dA1, ta.a1 + ko);
  gload16(buf + ta.dB0, ta.b0 + ko); gload16(buf + ta.dB1, ta.b1 + ko);
}
__device__ __forceinline__ void compute_step(
    const TileAddr& ta, const char* buf, f32x4 (&acc)[4][4]) {
  bf16x8 af[4], bfr[4];
  #pragma unroll
  for (int m = 0; m < 4; ++m) af[m] = *(const bf16x8*)(buf + ta.offA[m]);
  #pragma unroll
  for (int n = 0; n < 4; ++n) bfr[n] = *(const bf16x8*)(buf + ta.offB[n]);
  __builtin_amdgcn_s_setprio(1);
  #pragma unroll
  for (int m = 0; m < 4; ++m)
    #pragma unroll
    for (int n = 0; n < 4; ++n)
      acc[m][n] = __builtin_amdgcn_mfma_f32_16x16x32_bf16(af[m], bfr[n], acc[m][n], 0, 0, 0);
  __builtin_amdgcn_s_setprio(0);
}

// ---------------------------------------------------------------------------
// 2-phase double-buffered core (proven ~650 TF at high occupancy). 32 KB LDS.
// ---------------------------------------------------------------------------
template<int RM>
__device__ __forceinline__ void gemm128(
    char* lds, f32x4 (&acc)[4][4],
    const short* __restrict__ A, int lda,
    const short* __restrict__ BT, int ldb,
    int row0, int col0, int nkt, int tid, int wave, int lane) {
  TileAddr ta = mk_addr<RM>(A, lda, BT, ldb, row0, col0, tid, wave, lane);
  stage_to(ta, lds, 0);
  __syncthreads();
  for (int t = 0; t < nkt; ++t) {
    char* cur = lds + (t & 1) * 16384;
    char* nxt = lds + ((t + 1) & 1) * 16384;
    if (t + 1 < nkt) stage_to(ta, nxt, (t + 1) * 32);
    compute_step(ta, cur, acc);
    __syncthreads();   // drains vmcnt (next tile staged) + protects LDS
  }
}

// ---------------------------------------------------------------------------
// Depth-3 counted-vmcnt pipeline (round-5-proven schedule @128²). 64 KB LDS,
// 4 buffers; per iter: waitbar(tile t landed, 2 tiles stay in flight) ->
// stage(t+3) -> ds_read(t) -> MFMA. One barrier/K-step, vmcnt never 0 mid-loop.
// ---------------------------------------------------------------------------
template<int RM>
__device__ __forceinline__ void gemm128_d3(
    char* lds, f32x4 (&acc)[4][4],
    const short* __restrict__ A, int lda,
    const short* __restrict__ BT, int ldb,
    int row0, int col0, int nkt, int tid, int wave, int lane) {
  TileAddr ta = mk_addr<RM>(A, lda, BT, ldb, row0, col0, tid, wave, lane);
  #pragma unroll
  for (int p = 0; p < 3; ++p)
    stage_to(ta, lds + p * 16384, p * 32);
  for (int t = 0; t < nkt; ++t) {
    if (t < nkt - 2)       { asm volatile("s_waitcnt vmcnt(8)" ::: "memory"); }
    else if (t == nkt - 2) { asm volatile("s_waitcnt vmcnt(4)" ::: "memory"); }
    else                   { asm volatile("s_waitcnt vmcnt(0)" ::: "memory"); }
    __builtin_amdgcn_s_barrier();
    asm volatile("" ::: "memory");
    if (t + 3 < nkt) stage_to(ta, lds + ((t + 3) & 3) * 16384, (t + 3) * 32);
    compute_step(ta, lds + (t & 3) * 16384, acc);
  }
}

// epilogue: C/D layout col=lane&15, row=(lane>>4)*4+reg  [HW-verified]
// ADD: 0 none; 1 chunk-pair add (mul+1); 2 seg add (+64). OUT: 0 bf16; 1 fp32
template<int ADD, int OUT>
__device__ __forceinline__ void epi128(
    f32x4 (&acc)[4][4], void* __restrict__ Cp, int ldc,
    const short* __restrict__ AddP,
    int row0, int col0, int M, int wave, int lane) {
  const int wm = wave >> 1, wn = wave & 1;
  const int l16 = lane & 15;
  #pragma unroll
  for (int m = 0; m < 4; ++m) {
    #pragma unroll
    for (int n = 0; n < 4; ++n) {
      const int grow0 = row0 + wm * 64 + m * 16 + ((lane >> 4) << 2);
      const int gcol  = col0 + wn * 64 + n * 16 + l16;
      #pragma unroll
      for (int r = 0; r < 4; ++r) {
        const int R = grow0 + r;
        if (R < M) {
          float val = acc[m][n][r];
          if (ADD == 1) {
            int ar = (((R & 63) << 8) | ((R >> 6) << 1)) + 1;
            val += bf2fs(AddP[(size_t)ar * 1024 + gcol]);
          } else if (ADD == 2) {
            int ar = (((R >> 6) << 7) | (R & 63)) + 64;
            val += bf2fs(AddP[(size_t)ar * 1024 + gcol]);
          }
          if (OUT == 0) ((short*)Cp)[(size_t)R * ldc + gcol] = f2bfs(val);
          else          ((float*)Cp)[(size_t)R * ldc + gcol] = val;
        }
      }
    }
  }
}

// one 1024x1024 power-product unit: C = A * BT^T (bf16). D3 picks pipeline.
template<int D3>
__device__ __forceinline__ void run_unit(char* lds,
    const short* A, const short* BT, short* C,
    int tile, int tid, int wave, int lane) {
  f32x4 acc[4][4] = {};
  int row0 = (tile >> 3) * 128, col0 = (tile & 7) * 128;
  if (D3) gemm128_d3<0>(lds, acc, A, 1024, BT, 1024, row0, col0, 32, tid, wave, lane);
  else    gemm128<0>(lds, acc, A, 1024, BT, 1024, row0, col0, 32, tid, wave, lane);
  epi128<0, 0>(acc, C, 1024, nullptr, row0, col0, 1024, wave, lane);
}

// Slots: 0 UT, 1 U2T, 2 U4T, 3 U8T, 4 U16T, 5 U32T, 6 U64T, 7 U128T, 8 U256T,
//        9 Ub, 10 U2, 11 U4, 12 U8, 13 U16, 14 U32, 15 U64, 16 U128, 17 Wb

// ---------------- prep A: transposes (W^T, U^T) + casts (U, W) ----------------
__global__ __launch_bounds__(256) void k_prep_tc(
    const float* __restrict__ W, const float* __restrict__ Uf,
    short* __restrict__ BTcat, short* __restrict__ slab) {
  __shared__ float tf[32][36];
  int b = blockIdx.x, t = threadIdx.x;
  if (b < 2048) {
    const float* src = (b < 1024) ? W : Uf;
    int bb = b & 1023;
    int i0 = (bb >> 5) * 32, j0 = (bb & 31) * 32;
    int r = t >> 3, c = (t & 7) * 4;
    *(f32x4*)&tf[r][c] = *(const f32x4*)(src + (size_t)(i0 + r) * 1024 + j0 + c);
    __syncthreads();
    s16x4 o;
    o.x = f2bfs(tf[c + 0][r]); o.y = f2bfs(tf[c + 1][r]);
    o.z = f2bfs(tf[c + 2][r]); o.w = f2bfs(tf[c + 3][r]);
    if (b < 1024)  // W^T -> BTcat col-block 1 (K idx 1024..2047)
      *(s16x4*)(BTcat + (size_t)(j0 + r) * 2048 + 1024 + i0 + c) = o;
    else           // U^T -> slot 0
      *(s16x4*)(slab + (size_t)(j0 + r) * 1024 + i0 + c) = o;
  } else {
    int q = b - 2048;   // first 512 = U cast (slot 9), next 512 = W cast (slot 17)
    const float* src = (q < 512) ? Uf : W;
    short* dst = slab + (size_t)((q < 512) ? 9 : 17) * SLOT;
    int qq = q & 511;
    size_t base = (size_t)qq * 2048 + (size_t)t * 8;
    f32x4 a = *(const f32x4*)(src + base);
    f32x4 c2 = *(const f32x4*)(src + base + 4);
    bf16x8 o;
    o[0] = f2bfs(a.x);  o[1] = f2bfs(a.y);  o[2] = f2bfs(a.z);  o[3] = f2bfs(a.w);
    o[4] = f2bfs(c2.x); o[5] = f2bfs(c2.y); o[6] = f2bfs(c2.z); o[7] = f2bfs(c2.w);
    *(bf16x8*)(dst + base) = o;
  }
}

// ---------------- prep B: X cast (bf16) ----------------
__global__ __launch_bounds__(256) void k_prep_x(
    const float* __restrict__ X, short* __restrict__ XB) {
  int q = blockIdx.x, t = threadIdx.x;
  size_t base = ((size_t)q * 256 + t) * 32;
  #pragma unroll
  for (int i = 0; i < 4; ++i) {
    f32x4 a = *(const f32x4*)(X + base + i * 8);
    f32x4 c2 = *(const f32x4*)(X + base + i * 8 + 4);
    bf16x8 o;
    o[0] = f2bfs(a.x);  o[1] = f2bfs(a.y);  o[2] = f2bfs(a.z);  o[3] = f2bfs(a.w);
    o[4] = f2bfs(c2.x); o[5] = f2bfs(c2.y); o[6] = f2bfs(c2.z); o[7] = f2bfs(c2.w);
    *(bf16x8*)(XB + base + i * 8) = o;
  }
}

// ---------------- k_pre: U2T, U2, TW1T=(WU)^T -> BTcat block 0 (d3) ---------
__global__ __launch_bounds__(256) void k_pre(short* slab, short* BTcat) {
  __shared__ __align__(16) char lds[65536];
  int tid = threadIdx.x, wave = tid >> 6, lane = tid & 63;
  int b = blockIdx.x, u = b >> 6, q = b & 63;
  if (u == 0)       // U2T = g(UT, Ub) = U^T U^T = (U^2)^T
    run_unit<1>(lds, slab, slab + (size_t)9 * SLOT, slab + (size_t)1 * SLOT,
                q, tid, wave, lane);
  else if (u == 1)  // U2 = g(Ub, UT) = U U
    run_unit<1>(lds, slab + (size_t)9 * SLOT, slab, slab + (size_t)10 * SLOT,
                q, tid, wave, lane);
  else {  // TW1T = g(UT, Wb) = U^T W^T = (WU)^T -> BTcat cols [0,1024), ldc 2048
    f32x4 acc[4][4] = {};
    int row0 = (q >> 3) * 128, col0 = (q & 7) * 128;
    gemm128_d3<0>(lds, acc, slab, 1024, slab + (size_t)17 * SLOT, 1024,
                  row0, col0, 32, tid, wave, lane);
    epi128<0, 0>(acc, BTcat, 2048, nullptr, row0, col0, 1024, wave, lane);
  }
}

// ---------------- k_big: F0[16384][1024] = XB[16384x2048] * BTcat^T ---------
// F0 row R=b*256+s: x_{b,2s}*(WU) + x_{b,2s+1}*W  (XB viewed lda=2048)
// + fused squares U4T=g(U2T,U2), U4=g(U2,U2T). 2-phase core (high occupancy).
__global__ __launch_bounds__(256) void k_big(
    const short* __restrict__ XB, const short* __restrict__ BTcat,
    short* __restrict__ FA, short* slab) {
  __shared__ __align__(16) char lds[32768];
  int tid = threadIdx.x, wave = tid >> 6, lane = tid & 63;
  int b = blockIdx.x;
  if (b < 1024) {
    f32x4 acc[4][4] = {};
    int row0 = (b >> 3) * 128, col0 = (b & 7) * 128;   // col-fastest: L2 B-pinning
    gemm128<0>(lds, acc, XB, 2048, BTcat, 2048, row0, col0, 64, tid, wave, lane);
    epi128<0, 0>(acc, FA, 1024, nullptr, row0, col0, 16384, wave, lane);
  } else {
    int q = b - 1024, tl = q & 63;
    if (q < 64)
      run_unit<0>(lds, slab + (size_t)1 * SLOT, slab + (size_t)10 * SLOT,
                  slab + (size_t)2 * SLOT, tl, tid, wave, lane);   // U4T
    else
      run_unit<0>(lds, slab + (size_t)10 * SLOT, slab + (size_t)1 * SLOT,
                  slab + (size_t)11 * SLOT, tl, tid, wave, lane);  // U4
  }
}

// ---------------- tail level: combine (blocks < nComb) + 0-2 square units ---
// D3=1 for latency-bound small grids (deep intra-block pipeline, 64KB LDS).
template<int RM, int OUT, int D3>
__global__ __launch_bounds__(256) void k_lvl(
    const short* __restrict__ Fin, const short* __restrict__ PT,
    void* __restrict__ Fout, int M, int nComb,
    const short* __restrict__ sA0, const short* __restrict__ sB0, short* __restrict__ sC0,
    const short* __restrict__ sA1, const short* __restrict__ sB1, short* __restrict__ sC1) {
  constexpr int LSZ = D3 ? 65536 : 32768;
  __shared__ __align__(16) char lds[LSZ];
  int tid = threadIdx.x, wave = tid >> 6, lane = tid & 63;
  int b = blockIdx.x;
  if (b < nComb) {
    f32x4 acc[4][4] = {};
    int row0 = (b >> 3) * 128, col0 = (b & 7) * 128;
    if (D3) gemm128_d3<RM>(lds, acc, Fin, 1024, PT, 1024, row0, col0, 32, tid, wave, lane);
    else    gemm128<RM>(lds, acc, Fin, 1024, PT, 1024, row0, col0, 32, tid, wave, lane);
    epi128<RM, OUT>(acc, Fout, 1024, Fin, row0, col0, M, wave, lane);
  } else {
    int q = b - nComb;
    const short* sa = (q < 64) ? sA0 : sA1;
    const short* sb = (q < 64) ? sB0 : sB1;
    short* sc = (q < 64) ? sC0 : sC1;
    run_unit<D3>(lds, sa, sb, sc, q & 63, tid, wave, lane);
  }
}

extern "C" void kernel_launch(void* const* d_in, const int* in_sizes, int n_in,
                              void* d_out, int out_size, void* d_ws, size_t ws_size,
                              hipStream_t stream) {
  const float* X = (const float*)d_in[0];   // [64,512,1024] fp32
  const float* W = (const float*)d_in[1];   // [1024,1024] fp32
  const float* U = (const float*)d_in[2];   // [1024,1024] fp32
  float* outp = (float*)d_out;              // [64,1024] fp32

  char* ws = (char*)d_ws;
  short* XB    = (short*)ws;                          // [0,64MB) bf16 X (lda-2048 view)
  short* FB    = (short*)ws;                          // aliases XB (dead after k_big)
  short* BTcat = (short*)(ws + ((size_t)64 << 20));   // [64,68) bf16 [1024][2048]
  short* slab  = (short*)(ws + ((size_t)68 << 20));   // [68,104) 18 x 2MB slots
  short* FA    = (short*)(ws + ((size_t)104 << 20));  // [104,136) bf16 [16384][1024]
  auto sl = [&](int i) { return slab + (size_t)i * SLOT; };

  k_prep_tc<<<3072, 256, 0, stream>>>(W, U, BTcat, slab);
  k_prep_x<<<4096, 256, 0, stream>>>(X, XB);
  k_pre<<<192, 256, 0, stream>>>(slab, BTcat);
  k_big<<<1152, 256, 0, stream>>>(XB, BTcat, FA, slab);

  // ph0: M=8192 (RM1, U2T); sq U8T=g(U4T,U4), U8=g(U4,U4T)
  k_lvl<1, 0, 0><<<640, 256, 0, stream>>>(FA, sl(1), FB, 8192, 512,
                                          sl(2), sl(11), sl(3), sl(11), sl(2), sl(12));
  // ph1: M=4096 (RM2, U4T); sq U16T=g(U8T,U8), U16=g(U8,U8T)
  k_lvl<2, 0, 0><<<384, 256, 0, stream>>>(FB, sl(2), FA, 4096, 256,
                                          sl(3), sl(12), sl(4), sl(12), sl(3), sl(13));
  // ph2: M=2048 (U8T); sq U32T, U32   [d3]
  k_lvl<2, 0, 1><<<256, 256, 0, stream>>>(FA, sl(3), FB, 2048, 128,
                                          sl(4), sl(13), sl(5), sl(13), sl(4), sl(14));
  // ph3: M=1024 (U16T); sq U64T, U64  [d3]
  k_lvl<2, 0, 1><<<192, 256, 0, stream>>>(FB, sl(4), FA, 1024, 64,
                                          sl(5), sl(14), sl(6), sl(14), sl(5), sl(15));
  // ph4: M=512 (U32T); sq U128T, U128 [d3]
  k_lvl<2, 0, 1><<<160, 256, 0, stream>>>(FA, sl(5), FB, 512, 32,
                                          sl(6), sl(15), sl(7), sl(15), sl(6), sl(16));
  // ph5: M=256 (U64T); sq U256T only  [d3]
  k_lvl<2, 0, 1><<<80, 256, 0, stream>>>(FB, sl(6), FA, 256, 16,
                                         sl(7), sl(16), sl(8), nullptr, nullptr, nullptr);
  // ph6: M=128 (U128T)                [d3]
  k_lvl<2, 0, 1><<<8, 256, 0, stream>>>(FA, sl(7), FB, 128, 8,
                                        nullptr, nullptr, nullptr, nullptr, nullptr, nullptr);
  // ph7: M=64 (U256T), fp32 -> d_out  [d3]
  k_lvl<2, 1, 1><<<8, 256, 0, stream>>>(FB, sl(8), outp, 64, 8,
                                        nullptr, nullptr, nullptr, nullptr, nullptr, nullptr);
}

// Round 9
// 345.392 us; speedup vs baseline: 1.9124x; 1.1221x over previous
//
#include <hip/hip_runtime.h>
#include <hip/hip_bf16.h>

typedef __attribute__((ext_vector_type(4))) float f32x4;
typedef __attribute__((ext_vector_type(8))) short bf16x8;
typedef __attribute__((ext_vector_type(4))) short s16x4;

#define SLOT (1024 * 1024)   // elements per 2MB bf16 power slot

__device__ __forceinline__ short f2bfs(float f) {
  __hip_bfloat16 h = __float2bfloat16(f);   // RNE
  union { __hip_bfloat16 h; short s; } u; u.h = h;
  return u.s;
}
__device__ __forceinline__ float bf2fs(short s) {
  union { unsigned u; float f; } v; v.u = ((unsigned)(unsigned short)s) << 16;
  return v.f;
}

// async global->LDS, 16B/lane; LDS dest linear (wave base + lane*16)
__device__ __forceinline__ void gload16(void* l, const void* g) {
  __builtin_amdgcn_global_load_lds(
      (const __attribute__((address_space(1))) unsigned int*)g,
      (__attribute__((address_space(3))) unsigned int*)l, 16, 0, 0);
}

// RM=0 identity; RM=2 seg-major radix-2: mul=((R>>6)<<7)|(R&63)
// RM=3 C=4 chunk view of XB: row=(R&63)*512 + (R>>6)*4  (K-blocks are the
//      next 3 rows; linear since row-stride 1024 == K-block size)
template<int RM>
__device__ __forceinline__ int rmap(int R) {
  return (RM == 0) ? R
       : (RM == 3) ? (((R & 63) << 9) | ((R >> 6) << 2))
                   : (((R >> 6) << 7) | (R & 63));
}

// ---------------------------------------------------------------------------
// Per-thread addressing for 128x128 tile staging (A 128x32 + B 128x32 bf16).
// Swizzle: granule g at row r stored at g ^ ((r>>1)&3); involution on read.
// ---------------------------------------------------------------------------
struct TileAddr {
  const short *a0, *a1, *b0, *b1;
  int dA0, dA1, dB0, dB1;
  int offA[4], offB[4];
};
template<int RM>
__device__ __forceinline__ TileAddr mk_addr(
    const short* A, int lda, const short* BT, int ldb,
    int row0, int col0, int tid, int wave, int lane) {
  TileAddr t;
  const int wm = wave >> 1, wn = wave & 1;
  const int l16 = lane & 15, kg = lane >> 4;
  const int r0 = tid >> 2, g0 = tid & 3;
  const int gs0 = g0 ^ ((r0 >> 1) & 3);
  const int r1 = r0 + 64;
  const int gs1 = g0 ^ ((r1 >> 1) & 3);
  t.a0 = A + (size_t)rmap<RM>(row0 + r0) * lda + gs0 * 8;
  t.a1 = A + (size_t)rmap<RM>(row0 + r1) * lda + gs1 * 8;
  t.b0 = BT + (size_t)(col0 + r0) * ldb + gs0 * 8;
  t.b1 = BT + (size_t)(col0 + r1) * ldb + gs1 * 8;
  t.dA0 = tid * 16; t.dA1 = t.dA0 + 4096;
  t.dB0 = 8192 + tid * 16; t.dB1 = t.dB0 + 4096;
  #pragma unroll
  for (int m = 0; m < 4; ++m) {
    int row = wm * 64 + m * 16 + l16;
    t.offA[m] = (row * 4 + (kg ^ ((row >> 1) & 3))) * 16;
  }
  #pragma unroll
  for (int n = 0; n < 4; ++n) {
    int c = wn * 64 + n * 16 + l16;
    t.offB[n] = 8192 + (c * 4 + (kg ^ ((c >> 1) & 3))) * 16;
  }
  return t;
}
__device__ __forceinline__ void stage_to(const TileAddr& ta, char* buf, int ko) {
  gload16(buf + ta.dA0, ta.a0 + ko); gload16(buf + ta.dA1, ta.a1 + ko);
  gload16(buf + ta.dB0, ta.b0 + ko); gload16(buf + ta.dB1, ta.b1 + ko);
}
__device__ __forceinline__ void compute_step(
    const TileAddr& ta, const char* buf, f32x4 (&acc)[4][4]) {
  bf16x8 af[4], bfr[4];
  #pragma unroll
  for (int m = 0; m < 4; ++m) af[m] = *(const bf16x8*)(buf + ta.offA[m]);
  #pragma unroll
  for (int n = 0; n < 4; ++n) bfr[n] = *(const bf16x8*)(buf + ta.offB[n]);
  __builtin_amdgcn_s_setprio(1);
  #pragma unroll
  for (int m = 0; m < 4; ++m)
    #pragma unroll
    for (int n = 0; n < 4; ++n)
      acc[m][n] = __builtin_amdgcn_mfma_f32_16x16x32_bf16(af[m], bfr[n], acc[m][n], 0, 0, 0);
  __builtin_amdgcn_s_setprio(0);
}

// ---------------------------------------------------------------------------
// 2-phase double-buffered core (occupancy-driven). 32 KB LDS.
// ---------------------------------------------------------------------------
template<int RM>
__device__ __forceinline__ void gemm128(
    char* lds, f32x4 (&acc)[4][4],
    const short* __restrict__ A, int lda,
    const short* __restrict__ BT, int ldb,
    int row0, int col0, int nkt, int tid, int wave, int lane) {
  TileAddr ta = mk_addr<RM>(A, lda, BT, ldb, row0, col0, tid, wave, lane);
  stage_to(ta, lds, 0);
  __syncthreads();
  for (int t = 0; t < nkt; ++t) {
    char* cur = lds + (t & 1) * 16384;
    char* nxt = lds + ((t + 1) & 1) * 16384;
    if (t + 1 < nkt) stage_to(ta, nxt, (t + 1) * 32);
    compute_step(ta, cur, acc);
    __syncthreads();
  }
}

// ---------------------------------------------------------------------------
// Depth-3 counted-vmcnt pipeline (proven r5/r7/r8). 64 KB LDS, 4 buffers;
// per iter: vmcnt(8)+barrier (2 tiles stay in flight) -> stage(t+3) ->
// ds_read(t) -> MFMA. vmcnt never drains to 0 mid-loop.
// ---------------------------------------------------------------------------
template<int RM>
__device__ __forceinline__ void gemm128_d3(
    char* lds, f32x4 (&acc)[4][4],
    const short* __restrict__ A, int lda,
    const short* __restrict__ BT, int ldb,
    int row0, int col0, int nkt, int tid, int wave, int lane) {
  TileAddr ta = mk_addr<RM>(A, lda, BT, ldb, row0, col0, tid, wave, lane);
  #pragma unroll
  for (int p = 0; p < 3; ++p)
    stage_to(ta, lds + p * 16384, p * 32);
  for (int t = 0; t < nkt; ++t) {
    if (t < nkt - 2)       { asm volatile("s_waitcnt vmcnt(8)" ::: "memory"); }
    else if (t == nkt - 2) { asm volatile("s_waitcnt vmcnt(4)" ::: "memory"); }
    else                   { asm volatile("s_waitcnt vmcnt(0)" ::: "memory"); }
    __builtin_amdgcn_s_barrier();
    asm volatile("" ::: "memory");
    if (t + 3 < nkt) stage_to(ta, lds + ((t + 3) & 3) * 16384, (t + 3) * 32);
    compute_step(ta, lds + (t & 3) * 16384, acc);
  }
}

// epilogue: C/D layout col=lane&15, row=(lane>>4)*4+reg  [HW-verified]
// ADD: 0 none; 2 seg add (row+64, bf16). OUT: 0 bf16; 1 fp32
template<int ADD, int OUT>
__device__ __forceinline__ void epi128(
    f32x4 (&acc)[4][4], void* __restrict__ Cp, int ldc,
    const short* __restrict__ AddP,
    int row0, int col0, int M, int wave, int lane) {
  const int wm = wave >> 1, wn = wave & 1;
  const int l16 = lane & 15;
  #pragma unroll
  for (int m = 0; m < 4; ++m) {
    #pragma unroll
    for (int n = 0; n < 4; ++n) {
      const int grow0 = row0 + wm * 64 + m * 16 + ((lane >> 4) << 2);
      const int gcol  = col0 + wn * 64 + n * 16 + l16;
      #pragma unroll
      for (int r = 0; r < 4; ++r) {
        const int R = grow0 + r;
        if (R < M) {
          float val = acc[m][n][r];
          if (ADD == 2) {
            int ar = (((R >> 6) << 7) | (R & 63)) + 64;
            val += bf2fs(AddP[(size_t)ar * 1024 + gcol]);
          }
          if (OUT == 0) ((short*)Cp)[(size_t)R * ldc + gcol] = f2bfs(val);
          else          ((float*)Cp)[(size_t)R * ldc + gcol] = val;
        }
      }
    }
  }
}

// one 1024x1024 power-product unit: C = A * BT^T (bf16), ldc-general
template<int D3>
__device__ __forceinline__ void run_unit(char* lds,
    const short* A, const short* BT, short* C, int ldc,
    int tile, int tid, int wave, int lane) {
  f32x4 acc[4][4] = {};
  int row0 = (tile >> 3) * 128, col0 = (tile & 7) * 128;
  if (D3) gemm128_d3<0>(lds, acc, A, 1024, BT, 1024, row0, col0, 32, tid, wave, lane);
  else    gemm128<0>(lds, acc, A, 1024, BT, 1024, row0, col0, 32, tid, wave, lane);
  epi128<0, 0>(acc, C, ldc, nullptr, row0, col0, 1024, wave, lane);
}

// Slots: 0 UT, 1 U2T, 2 U4T, 3 U8T, 4 U16T, 5 U32T, 6 U64T, 7 U128T, 8 U256T,
//        9 Ub, 10 U2, 11 U4, 12 U8, 13 U16, 14 U32, 15 U64, 16 WU1/U128, 17 Wb

// ---------------- prep A: transposes (W^T -> BTcat blk3, U^T) + casts -------
__global__ __launch_bounds__(256) void k_prep_tc(
    const float* __restrict__ W, const float* __restrict__ Uf,
    short* __restrict__ BTcat, short* __restrict__ slab) {
  __shared__ float tf[32][36];
  int b = blockIdx.x, t = threadIdx.x;
  if (b < 2048) {
    const float* src = (b < 1024) ? W : Uf;
    int bb = b & 1023;
    int i0 = (bb >> 5) * 32, j0 = (bb & 31) * 32;
    int r = t >> 3, c = (t & 7) * 4;
    *(f32x4*)&tf[r][c] = *(const f32x4*)(src + (size_t)(i0 + r) * 1024 + j0 + c);
    __syncthreads();
    s16x4 o;
    o.x = f2bfs(tf[c + 0][r]); o.y = f2bfs(tf[c + 1][r]);
    o.z = f2bfs(tf[c + 2][r]); o.w = f2bfs(tf[c + 3][r]);
    if (b < 1024)  // W^T -> BTcat col-block 3 (K idx 3072..4095)
      *(s16x4*)(BTcat + (size_t)(j0 + r) * 4096 + 3072 + i0 + c) = o;
    else           // U^T -> slot 0
      *(s16x4*)(slab + (size_t)(j0 + r) * 1024 + i0 + c) = o;
  } else {
    int q = b - 2048;   // first 512 = U cast (slot 9), next 512 = W cast (slot 17)
    const float* src = (q < 512) ? Uf : W;
    short* dst = slab + (size_t)((q < 512) ? 9 : 17) * SLOT;
    int qq = q & 511;
    size_t base = (size_t)qq * 2048 + (size_t)t * 8;
    f32x4 a = *(const f32x4*)(src + base);
    f32x4 c2 = *(const f32x4*)(src + base + 4);
    bf16x8 o;
    o[0] = f2bfs(a.x);  o[1] = f2bfs(a.y);  o[2] = f2bfs(a.z);  o[3] = f2bfs(a.w);
    o[4] = f2bfs(c2.x); o[5] = f2bfs(c2.y); o[6] = f2bfs(c2.z); o[7] = f2bfs(c2.w);
    *(bf16x8*)(dst + base) = o;
  }
}

// ---------------- pre1 + X cast fused (32KB LDS so X-cast blocks stack) -----
// units (b<256): U2T=g(UT,Ub)->1, U2=g(Ub,UT)->10, TW1T=g(UT,Wb)->BTcat blk2,
//                WU1=g(Wb,UT)->16;  b>=256: X cast
__global__ __launch_bounds__(256) void k_pre1x(
    const float* __restrict__ X, short* __restrict__ XB,
    short* slab, short* BTcat) {
  __shared__ __align__(16) char lds[32768];
  int tid = threadIdx.x;
  int b = blockIdx.x;
  if (b < 256) {
    int wave = tid >> 6, lane = tid & 63;
    int u = b >> 6, q = b & 63;
    short* s = slab;
    if (u == 0)
      run_unit<0>(lds, s, s + (size_t)9 * SLOT, s + (size_t)1 * SLOT, 1024, q, tid, wave, lane);
    else if (u == 1)
      run_unit<0>(lds, s + (size_t)9 * SLOT, s, s + (size_t)10 * SLOT, 1024, q, tid, wave, lane);
    else if (u == 2)
      run_unit<0>(lds, s, s + (size_t)17 * SLOT, BTcat + 2048, 4096, q, tid, wave, lane);
    else
      run_unit<0>(lds, s + (size_t)17 * SLOT, s, s + (size_t)16 * SLOT, 1024, q, tid, wave, lane);
  } else {
    int q = b - 256;
    size_t base = ((size_t)q * 256 + tid) * 32;
    #pragma unroll
    for (int i = 0; i < 4; ++i) {
      f32x4 a = *(const f32x4*)(X + base + i * 8);
      f32x4 c2 = *(const f32x4*)(X + base + i * 8 + 4);
      bf16x8 o;
      o[0] = f2bfs(a.x);  o[1] = f2bfs(a.y);  o[2] = f2bfs(a.z);  o[3] = f2bfs(a.w);
      o[4] = f2bfs(c2.x); o[5] = f2bfs(c2.y); o[6] = f2bfs(c2.z); o[7] = f2bfs(c2.w);
      *(bf16x8*)(XB + base + i * 8) = o;
    }
  }
}

// ---------------- pre2: TW2T, TW3T -> BTcat blk1/blk0; U4T, U4 (d3) ---------
__global__ __launch_bounds__(256) void k_pre2(short* slab, short* BTcat) {
  __shared__ __align__(16) char lds[65536];
  int tid = threadIdx.x, wave = tid >> 6, lane = tid & 63;
  int b = blockIdx.x, u = b >> 6, q = b & 63;
  short* s = slab;
  if (u == 0)       // TW2T = g(U2T, Wb) = (W U^2)^T
    run_unit<1>(lds, s + (size_t)1 * SLOT, s + (size_t)17 * SLOT, BTcat + 1024, 4096, q, tid, wave, lane);
  else if (u == 1)  // TW3T = g(U2T, WU1) = (W U^3)^T
    run_unit<1>(lds, s + (size_t)1 * SLOT, s + (size_t)16 * SLOT, BTcat, 4096, q, tid, wave, lane);
  else if (u == 2)  // U4T = g(U2T, U2)
    run_unit<1>(lds, s + (size_t)1 * SLOT, s + (size_t)10 * SLOT, s + (size_t)2 * SLOT, 1024, q, tid, wave, lane);
  else              // U4 = g(U2, U2T)
    run_unit<1>(lds, s + (size_t)10 * SLOT, s + (size_t)1 * SLOT, s + (size_t)11 * SLOT, 1024, q, tid, wave, lane);
}

// ---------------- k_big: F0[8192][1024] = XB_chunk4[8192x4096] * BTcat^T ----
// F0 row R=(s<<6)|b: sum_j x_{b,4s+j} * (W U^{3-j});  + sq U8T, U8 (b<128)
__global__ __launch_bounds__(256) void k_big(
    const short* __restrict__ XB, const short* __restrict__ BTcat,
    short* __restrict__ FA, short* slab) {
  __shared__ __align__(16) char lds[65536];
  int tid = threadIdx.x, wave = tid >> 6, lane = tid & 63;
  int b = blockIdx.x;
  short* s = slab;
  if (b < 128) {
    int q = b & 63;
    if (b < 64)  // U8T = g(U4T, U4)
      run_unit<1>(lds, s + (size_t)2 * SLOT, s + (size_t)11 * SLOT, s + (size_t)3 * SLOT, 1024, q, tid, wave, lane);
    else         // U8 = g(U4, U4T)
      run_unit<1>(lds, s + (size_t)11 * SLOT, s + (size_t)2 * SLOT, s + (size_t)12 * SLOT, 1024, q, tid, wave, lane);
  } else {
    int c = b - 128;
    f32x4 acc[4][4] = {};
    int row0 = (c >> 3) * 128, col0 = (c & 7) * 128;   // col-fastest
    gemm128_d3<3>(lds, acc, XB, 1024, BTcat, 4096, row0, col0, 128, tid, wave, lane);
    epi128<0, 0>(acc, FA, 1024, nullptr, row0, col0, 8192, wave, lane);
  }
}

// ---------------- tree level: combine (b < nComb) + 0-2 square units (d3) ---
template<int OUT>
__global__ __launch_bounds__(256) void k_lvl(
    const short* __restrict__ Fin, const short* __restrict__ PT,
    void* __restrict__ Fout, int M, int nComb,
    const short* __restrict__ sA0, const short* __restrict__ sB0, short* __restrict__ sC0,
    const short* __restrict__ sA1, const short* __restrict__ sB1, short* __restrict__ sC1) {
  __shared__ __align__(16) char lds[65536];
  int tid = threadIdx.x, wave = tid >> 6, lane = tid & 63;
  int b = blockIdx.x;
  if (b < nComb) {
    f32x4 acc[4][4] = {};
    int row0 = (b >> 3) * 128, col0 = (b & 7) * 128;
    gemm128_d3<2>(lds, acc, Fin, 1024, PT, 1024, row0, col0, 32, tid, wave, lane);
    epi128<2, OUT>(acc, Fout, 1024, Fin, row0, col0, M, wave, lane);
  } else {
    int q = b - nComb;
    const short* sa = (q < 64) ? sA0 : sA1;
    const short* sb = (q < 64) ? sB0 : sB1;
    short* sc = (q < 64) ? sC0 : sC1;
    run_unit<1>(lds, sa, sb, sc, 1024, q & 63, tid, wave, lane);
  }
}

extern "C" void kernel_launch(void* const* d_in, const int* in_sizes, int n_in,
                              void* d_out, int out_size, void* d_ws, size_t ws_size,
                              hipStream_t stream) {
  const float* X = (const float*)d_in[0];   // [64,512,1024] fp32
  const float* W = (const float*)d_in[1];   // [1024,1024] fp32
  const float* U = (const float*)d_in[2];   // [1024,1024] fp32
  float* outp = (float*)d_out;              // [64,1024] fp32

  char* ws = (char*)d_ws;
  short* XB    = (short*)ws;                          // [0,64MB) bf16 X
  short* FB    = (short*)ws;                          // aliases XB (dead after k_big)
  short* BTcat = (short*)(ws + ((size_t)64 << 20));   // [64,72) bf16 [1024][4096]
  short* slab  = (short*)(ws + ((size_t)72 << 20));   // [72,108) 18 x 2MB slots
  short* FA    = (short*)(ws + ((size_t)108 << 20));  // [108,124) bf16 [8192][1024]
  auto sl = [&](int i) { return slab + (size_t)i * SLOT; };

  k_prep_tc<<<3072, 256, 0, stream>>>(W, U, BTcat, slab);
  k_pre1x<<<4352, 256, 0, stream>>>(X, XB, slab, BTcat);
  k_pre2<<<256, 256, 0, stream>>>(slab, BTcat);
  k_big<<<640, 256, 0, stream>>>(XB, BTcat, FA, slab);

  // ph0: M=4096 (P=U4T); sq U16T=g(U8T,U8), U16=g(U8,U8T)
  k_lvl<0><<<384, 256, 0, stream>>>(FA, sl(2), FB, 4096, 256,
                                    sl(3), sl(12), sl(4), sl(12), sl(3), sl(13));
  // ph1: M=2048 (P=U8T); sq U32T, U32
  k_lvl<0><<<256, 256, 0, stream>>>(FB, sl(3), FA, 2048, 128,
                                    sl(4), sl(13), sl(5), sl(13), sl(4), sl(14));
  // ph2: M=1024 (P=U16T); sq U64T, U64
  k_lvl<0><<<192, 256, 0, stream>>>(FA, sl(4), FB, 1024, 64,
                                    sl(5), sl(14), sl(6), sl(14), sl(5), sl(15));
  // ph3: M=512 (P=U32T); sq U128T, U128 (U128 -> slot16, WU1 dead)
  k_lvl<0><<<160, 256, 0, stream>>>(FB, sl(5), FA, 512, 32,
                                    sl(6), sl(15), sl(7), sl(15), sl(6), sl(16));
  // ph4: M=256 (P=U64T); sq U256T only
  k_lvl<0><<<80, 256, 0, stream>>>(FA, sl(6), FB, 256, 16,
                                   sl(7), sl(16), sl(8), nullptr, nullptr, nullptr);
  // ph5: M=128 (P=U128T)
  k_lvl<0><<<8, 256, 0, stream>>>(FB, sl(7), FA, 128, 8,
                                  nullptr, nullptr, nullptr, nullptr, nullptr, nullptr);
  // ph6: M=64 (P=U256T), fp32 -> d_out
  k_lvl<1><<<8, 256, 0, stream>>>(FA, sl(8), outp, 64, 8,
                                  nullptr, nullptr, nullptr, nullptr, nullptr, nullptr);
}

// Round 10
// 327.146 us; speedup vs baseline: 2.0191x; 1.0558x over previous
//
#include <hip/hip_runtime.h>
#include <hip/hip_bf16.h>

typedef __attribute__((ext_vector_type(4))) float f32x4;
typedef __attribute__((ext_vector_type(8))) short bf16x8;
typedef __attribute__((ext_vector_type(4))) short s16x4;

#define SLOT (1024 * 1024)   // elements per 2MB bf16 power slot

__device__ __forceinline__ short f2bfs(float f) {
  __hip_bfloat16 h = __float2bfloat16(f);   // RNE
  union { __hip_bfloat16 h; short s; } u; u.h = h;
  return u.s;
}
__device__ __forceinline__ float bf2fs(short s) {
  union { unsigned u; float f; } v; v.u = ((unsigned)(unsigned short)s) << 16;
  return v.f;
}

// async global->LDS, 16B/lane; LDS dest linear (wave base + lane*16)
__device__ __forceinline__ void gload16(void* l, const void* g) {
  __builtin_amdgcn_global_load_lds(
      (const __attribute__((address_space(1))) unsigned int*)g,
      (__attribute__((address_space(3))) unsigned int*)l, 16, 0, 0);
}

// RM=0 identity; RM=2 seg-major radix-2: mul=((R>>6)<<7)|(R&63)
// RM=3 C=4 chunk view of XB: row=(R&63)*512 + (R>>6)*4 (K-blocks = next rows)
template<int RM>
__device__ __forceinline__ int rmap(int R) {
  return (RM == 0) ? R
       : (RM == 3) ? (((R & 63) << 9) | ((R >> 6) << 2))
                   : (((R >> 6) << 7) | (R & 63));
}

// ===========================================================================
// epilogue (shared by all cores): C/D layout col=lane&15, row=(lane>>4)*4+reg
// waves decompose 4x2 (wm=wave>>1, wn=wave&1); per-wave 64x64 tile.
// ADD: 0 none; 2 seg add (row+64, bf16). OUT: 0 bf16; 1 fp32
// ===========================================================================
template<int ADD, int OUT>
__device__ __forceinline__ void epi128(
    f32x4 (&acc)[4][4], void* __restrict__ Cp, int ldc,
    const short* __restrict__ AddP,
    int row0, int col0, int M, int wave, int lane) {
  const int wm = wave >> 1, wn = wave & 1;
  const int l16 = lane & 15;
  #pragma unroll
  for (int m = 0; m < 4; ++m) {
    #pragma unroll
    for (int n = 0; n < 4; ++n) {
      const int grow0 = row0 + wm * 64 + m * 16 + ((lane >> 4) << 2);
      const int gcol  = col0 + wn * 64 + n * 16 + l16;
      #pragma unroll
      for (int r = 0; r < 4; ++r) {
        const int R = grow0 + r;
        if (R < M) {
          float val = acc[m][n][r];
          if (ADD == 2) {
            int ar = (((R >> 6) << 7) | (R & 63)) + 64;
            val += bf2fs(AddP[(size_t)ar * 1024 + gcol]);
          }
          if (OUT == 0) ((short*)Cp)[(size_t)R * ldc + gcol] = f2bfs(val);
          else          ((float*)Cp)[(size_t)R * ldc + gcol] = val;
        }
      }
    }
  }
}

// ===========================================================================
// d3 core (proven r7-r9): 128x128 tile, 256 thr, 4 waves 2x2, depth-3 vmcnt.
// ===========================================================================
struct TileAddr {
  const short *a0, *a1, *b0, *b1;
  int dA0, dA1, dB0, dB1;
  int offA[4], offB[4];
};
template<int RM>
__device__ __forceinline__ TileAddr mk_addr(
    const short* A, int lda, const short* BT, int ldb,
    int row0, int col0, int tid, int wave, int lane) {
  TileAddr t;
  const int wm = wave >> 1, wn = wave & 1;
  const int l16 = lane & 15, kg = lane >> 4;
  const int r0 = tid >> 2, g0 = tid & 3;
  const int gs0 = g0 ^ ((r0 >> 1) & 3);
  const int r1 = r0 + 64;
  const int gs1 = g0 ^ ((r1 >> 1) & 3);
  t.a0 = A + (size_t)rmap<RM>(row0 + r0) * lda + gs0 * 8;
  t.a1 = A + (size_t)rmap<RM>(row0 + r1) * lda + gs1 * 8;
  t.b0 = BT + (size_t)(col0 + r0) * ldb + gs0 * 8;
  t.b1 = BT + (size_t)(col0 + r1) * ldb + gs1 * 8;
  t.dA0 = tid * 16; t.dA1 = t.dA0 + 4096;
  t.dB0 = 8192 + tid * 16; t.dB1 = t.dB0 + 4096;
  #pragma unroll
  for (int m = 0; m < 4; ++m) {
    int row = wm * 64 + m * 16 + l16;
    t.offA[m] = (row * 4 + (kg ^ ((row >> 1) & 3))) * 16;
  }
  #pragma unroll
  for (int n = 0; n < 4; ++n) {
    int c = wn * 64 + n * 16 + l16;
    t.offB[n] = 8192 + (c * 4 + (kg ^ ((c >> 1) & 3))) * 16;
  }
  return t;
}
__device__ __forceinline__ void stage_to(const TileAddr& ta, char* buf, int ko) {
  gload16(buf + ta.dA0, ta.a0 + ko); gload16(buf + ta.dA1, ta.a1 + ko);
  gload16(buf + ta.dB0, ta.b0 + ko); gload16(buf + ta.dB1, ta.b1 + ko);
}
__device__ __forceinline__ void compute_step(
    const TileAddr& ta, const char* buf, f32x4 (&acc)[4][4]) {
  bf16x8 af[4], bfr[4];
  #pragma unroll
  for (int m = 0; m < 4; ++m) af[m] = *(const bf16x8*)(buf + ta.offA[m]);
  #pragma unroll
  for (int n = 0; n < 4; ++n) bfr[n] = *(const bf16x8*)(buf + ta.offB[n]);
  __builtin_amdgcn_s_setprio(1);
  #pragma unroll
  for (int m = 0; m < 4; ++m)
    #pragma unroll
    for (int n = 0; n < 4; ++n)
      acc[m][n] = __builtin_amdgcn_mfma_f32_16x16x32_bf16(af[m], bfr[n], acc[m][n], 0, 0, 0);
  __builtin_amdgcn_s_setprio(0);
}
template<int RM>
__device__ __forceinline__ void gemm128_d3(
    char* lds, f32x4 (&acc)[4][4],
    const short* __restrict__ A, int lda,
    const short* __restrict__ BT, int ldb,
    int row0, int col0, int nkt, int tid, int wave, int lane) {
  TileAddr ta = mk_addr<RM>(A, lda, BT, ldb, row0, col0, tid, wave, lane);
  #pragma unroll
  for (int p = 0; p < 3; ++p)
    stage_to(ta, lds + p * 16384, p * 32);
  for (int t = 0; t < nkt; ++t) {
    if (t < nkt - 2)       { asm volatile("s_waitcnt vmcnt(8)" ::: "memory"); }
    else if (t == nkt - 2) { asm volatile("s_waitcnt vmcnt(4)" ::: "memory"); }
    else                   { asm volatile("s_waitcnt vmcnt(0)" ::: "memory"); }
    __builtin_amdgcn_s_barrier();
    asm volatile("" ::: "memory");
    if (t + 3 < nkt) stage_to(ta, lds + ((t + 3) & 3) * 16384, (t + 3) * 32);
    compute_step(ta, lds + (t & 3) * 16384, acc);
  }
}
__device__ __forceinline__ void run_unit_d3(char* lds,
    const short* A, const short* BT, short* C, int ldc,
    int tile, int tid, int wave, int lane) {
  f32x4 acc[4][4] = {};
  int row0 = (tile >> 3) * 128, col0 = (tile & 7) * 128;
  gemm128_d3<0>(lds, acc, A, 1024, BT, 1024, row0, col0, 32, tid, wave, lane);
  epi128<0, 0>(acc, C, ldc, nullptr, row0, col0, 1024, wave, lane);
}

// ===========================================================================
// 8-phase-style core (NEW): 256x128 tile, 512 thr, 8 waves 4x2 (64x64/wave).
// BK=64; 2 fine phases per K-tile: {barrier; ds_reads; stage; setprio+16 MFMA}.
// A triple-buffered (stage kt+2 at Q0), B double-buffered (stage kt+2 at Q1).
// vmcnt(6) at Q0-entry (ledger: 6 newest = SA(kt+1)+SB(kt+1) -> kt landed);
// vmcnt(0) at final K-tile (its successors' stages are suppressed).
// LDS: A 3x32KB [0,98304) + B 2x16KB [98304,131072).
// ===========================================================================
template<int RM>
__device__ __forceinline__ void gemm8ph(
    char* lds, f32x4 (&acc)[4][4],
    const short* __restrict__ A, int lda,
    const short* __restrict__ BT, int ldb,
    int row0, int col0, int nkt, int tid, int wave, int lane) {
  const int wm = wave >> 1, wn = wave & 1;
  const int l16 = lane & 15, kg = (lane >> 4) & 3;

  // staging source pointers
  const short* aP[2][2];   // [load l][half h] ; half h = tile rows h*128..
  #pragma unroll
  for (int l = 0; l < 2; ++l) {
    int G = l * 512 + tid;
    int rp = G >> 3, gs = (G & 7) ^ (rp & 7);
    #pragma unroll
    for (int h = 0; h < 2; ++h)
      aP[l][h] = A + (size_t)rmap<RM>(row0 + h * 128 + rp) * lda + gs * 8;
  }
  const short* bP[2];      // [half]: cols h*64..h*64+63
  {
    int rp = tid >> 3, gs = (tid & 7) ^ (rp & 7);
    #pragma unroll
    for (int h = 0; h < 2; ++h)
      bP[h] = BT + (size_t)(col0 + h * 64 + rp) * ldb + gs * 8;
  }

  // fragment read offsets (sans dbuf term)
  int offA[4][2], offB[4][2];
  #pragma unroll
  for (int m = 0; m < 4; ++m) {
    int rp = (wm & 1) * 64 + m * 16 + l16;
    #pragma unroll
    for (int ks = 0; ks < 2; ++ks) {
      int gsrc = ks * 4 + kg;
      offA[m][ks] = (wm >> 1) * 16384 + (rp * 8 + (gsrc ^ (rp & 7))) * 16;
    }
  }
  #pragma unroll
  for (int n = 0; n < 4; ++n) {
    int rp = n * 16 + l16;
    #pragma unroll
    for (int ks = 0; ks < 2; ++ks) {
      int gsrc = ks * 4 + kg;
      offB[n][ks] = wn * 8192 + (rp * 8 + (gsrc ^ (rp & 7))) * 16;
    }
  }

  auto SA = [&](int kt, int ad_t, int h) {   // 2 gloads
    char* dst = lds + ad_t * 32768 + h * 16384 + tid * 16;
    gload16(dst,        aP[0][h] + kt * 64);
    gload16(dst + 8192, aP[1][h] + kt * 64);
  };
  auto SB = [&](int kt, int h) {             // 1 gload
    gload16(lds + 98304 + (kt & 1) * 16384 + h * 8192 + tid * 16,
            bP[h] + kt * 64);
  };

  // prologue: A(0),B(0),A(1),B(1) staged; order chosen for the vmcnt ledger
  SA(0, 0, 0); SA(0, 0, 1);
  SB(0, 0); SB(0, 1);
  SA(1, 1, 0); SA(1, 1, 1);
  SB(1, 0); SB(1, 1);

  bf16x8 bR[4][2];
  int ad = 0;   // A dbuf of current kt (cycles 0,1,2)
  for (int kt = 0; kt < nkt; ++kt) {
    char* baseA = lds + ad * 32768;
    char* baseB = lds + 98304 + (kt & 1) * 16384;
    const int ad2 = (ad >= 1) ? ad - 1 : 2;   // (ad+2)%3 : dbuf of kt+2
    // ---------------- phase Q0 ----------------
    if (kt == nkt - 1) { asm volatile("s_waitcnt vmcnt(0)" ::: "memory"); }
    else               { asm volatile("s_waitcnt vmcnt(6)" ::: "memory"); }
    __builtin_amdgcn_s_barrier();
    __builtin_amdgcn_sched_barrier(0);
    {
      #pragma unroll
      for (int n = 0; n < 4; ++n)
        #pragma unroll
        for (int ks = 0; ks < 2; ++ks)
          bR[n][ks] = *(const bf16x8*)(baseB + offB[n][ks]);
      bf16x8 aR[2][2];
      #pragma unroll
      for (int mm = 0; mm < 2; ++mm)
        #pragma unroll
        for (int ks = 0; ks < 2; ++ks)
          aR[mm][ks] = *(const bf16x8*)(baseA + offA[mm][ks]);
      if (kt + 2 < nkt) { SA(kt + 2, ad2, 0); SA(kt + 2, ad2, 1); }
      __builtin_amdgcn_s_setprio(1);
      #pragma unroll
      for (int mm = 0; mm < 2; ++mm)
        #pragma unroll
        for (int n = 0; n < 4; ++n)
          #pragma unroll
          for (int ks = 0; ks < 2; ++ks)
            acc[mm][n] = __builtin_amdgcn_mfma_f32_16x16x32_bf16(
                aR[mm][ks], bR[n][ks], acc[mm][n], 0, 0, 0);
      __builtin_amdgcn_s_setprio(0);
    }
    // ---------------- phase Q1 ----------------
    __builtin_amdgcn_s_barrier();
    __builtin_amdgcn_sched_barrier(0);
    {
      bf16x8 aR[2][2];
      #pragma unroll
      for (int mm = 0; mm < 2; ++mm)
        #pragma unroll
        for (int ks = 0; ks < 2; ++ks)
          aR[mm][ks] = *(const bf16x8*)(baseA + offA[2 + mm][ks]);
      if (kt + 2 < nkt) { SB(kt + 2, 0); SB(kt + 2, 1); }
      __builtin_amdgcn_s_setprio(1);
      #pragma unroll
      for (int mm = 0; mm < 2; ++mm)
        #pragma unroll
        for (int n = 0; n < 4; ++n)
          #pragma unroll
          for (int ks = 0; ks < 2; ++ks)
            acc[2 + mm][n] = __builtin_amdgcn_mfma_f32_16x16x32_bf16(
                aR[mm][ks], bR[n][ks], acc[2 + mm][n], 0, 0, 0);
      __builtin_amdgcn_s_setprio(0);
    }
    ad = (ad == 2) ? 0 : ad + 1;
  }
}

// 1024x1024 unit on the 8ph core: C = A * BT^T, tiles 256x128 (32 tiles)
__device__ __forceinline__ void run_unit8(char* lds,
    const short* A, const short* BT, short* C, int ldc,
    int tile, int tid, int wave, int lane) {
  f32x4 acc[4][4] = {};
  int row0 = (tile >> 3) * 256, col0 = (tile & 7) * 128;
  gemm8ph<0>(lds, acc, A, 1024, BT, 1024, row0, col0, 16, tid, wave, lane);
  epi128<0, 0>(acc, C, ldc, nullptr, row0, col0, 1024, wave, lane);
}

// Slots: 0 UT, 1 U2T, 2 U4T, 3 U8T, 4 U16T, 5 U32T, 6 U64T, 7 U128T, 8 U256T,
//        9 Ub, 10 U2, 11 U4, 12 U8, 13 U16, 14 U32, 15 U64, 16 WU1/U128, 17 Wb

// ---------------- k_prep: transposes + bf16 casts (incl. X) ----------------
__global__ __launch_bounds__(256) void k_prep(
    const float* __restrict__ W, const float* __restrict__ Uf,
    const float* __restrict__ X,
    short* __restrict__ BTcat, short* __restrict__ slab, short* __restrict__ XB) {
  __shared__ float tf[32][36];
  int b = blockIdx.x, t = threadIdx.x;
  if (b < 2048) {
    const float* src = (b < 1024) ? W : Uf;
    int bb = b & 1023;
    int i0 = (bb >> 5) * 32, j0 = (bb & 31) * 32;
    int r = t >> 3, c = (t & 7) * 4;
    *(f32x4*)&tf[r][c] = *(const f32x4*)(src + (size_t)(i0 + r) * 1024 + j0 + c);
    __syncthreads();
    s16x4 o;
    o.x = f2bfs(tf[c + 0][r]); o.y = f2bfs(tf[c + 1][r]);
    o.z = f2bfs(tf[c + 2][r]); o.w = f2bfs(tf[c + 3][r]);
    if (b < 1024)  // W^T -> BTcat col-block 3 (K idx 3072..4095)
      *(s16x4*)(BTcat + (size_t)(j0 + r) * 4096 + 3072 + i0 + c) = o;
    else           // U^T -> slot 0
      *(s16x4*)(slab + (size_t)(j0 + r) * 1024 + i0 + c) = o;
  } else if (b < 3072) {
    int q = b - 2048;   // first 512 = U cast (slot 9), next 512 = W cast (17)
    const float* src = (q < 512) ? Uf : W;
    short* dst = slab + (size_t)((q < 512) ? 9 : 17) * SLOT;
    int qq = q & 511;
    size_t base = (size_t)qq * 2048 + (size_t)t * 8;
    f32x4 a = *(const f32x4*)(src + base);
    f32x4 c2 = *(const f32x4*)(src + base + 4);
    bf16x8 o;
    o[0] = f2bfs(a.x);  o[1] = f2bfs(a.y);  o[2] = f2bfs(a.z);  o[3] = f2bfs(a.w);
    o[4] = f2bfs(c2.x); o[5] = f2bfs(c2.y); o[6] = f2bfs(c2.z); o[7] = f2bfs(c2.w);
    *(bf16x8*)(dst + base) = o;
  } else {
    int q = b - 3072;   // 0..4095: X cast
    size_t base = ((size_t)q * 256 + t) * 32;
    #pragma unroll
    for (int i = 0; i < 4; ++i) {
      f32x4 a = *(const f32x4*)(X + base + i * 8);
      f32x4 c2 = *(const f32x4*)(X + base + i * 8 + 4);
      bf16x8 o;
      o[0] = f2bfs(a.x);  o[1] = f2bfs(a.y);  o[2] = f2bfs(a.z);  o[3] = f2bfs(a.w);
      o[4] = f2bfs(c2.x); o[5] = f2bfs(c2.y); o[6] = f2bfs(c2.z); o[7] = f2bfs(c2.w);
      *(bf16x8*)(XB + base + i * 8) = o;
    }
  }
}

// ---------------- k_pre1: U2T, U2, TW1T -> BTcat blk2, WU1 (8ph units) ------
__global__ __launch_bounds__(512) void k_pre1(short* slab, short* BTcat) {
  __shared__ __align__(16) char lds[131072];
  int tid = threadIdx.x, wave = tid >> 6, lane = tid & 63;
  int b = blockIdx.x, u = b >> 5, q = b & 31;
  short* s = slab;
  if (u == 0)       // U2T = g(UT, Ub)
    run_unit8(lds, s, s + (size_t)9 * SLOT, s + (size_t)1 * SLOT, 1024, q, tid, wave, lane);
  else if (u == 1)  // U2 = g(Ub, UT)
    run_unit8(lds, s + (size_t)9 * SLOT, s, s + (size_t)10 * SLOT, 1024, q, tid, wave, lane);
  else if (u == 2)  // TW1T = g(UT, Wb) = (WU)^T
    run_unit8(lds, s, s + (size_t)17 * SLOT, BTcat + 2048, 4096, q, tid, wave, lane);
  else              // WU1 = g(Wb, UT) = W*U
    run_unit8(lds, s + (size_t)17 * SLOT, s, s + (size_t)16 * SLOT, 1024, q, tid, wave, lane);
}

// ---------------- k_pre2: TW2T, TW3T -> BTcat blk1/0; U4T, U4 (8ph) ---------
__global__ __launch_bounds__(512) void k_pre2(short* slab, short* BTcat) {
  __shared__ __align__(16) char lds[131072];
  int tid = threadIdx.x, wave = tid >> 6, lane = tid & 63;
  int b = blockIdx.x, u = b >> 5, q = b & 31;
  short* s = slab;
  if (u == 0)       // TW2T = g(U2T, Wb)
    run_unit8(lds, s + (size_t)1 * SLOT, s + (size_t)17 * SLOT, BTcat + 1024, 4096, q, tid, wave, lane);
  else if (u == 1)  // TW3T = g(U2T, WU1)
    run_unit8(lds, s + (size_t)1 * SLOT, s + (size_t)16 * SLOT, BTcat, 4096, q, tid, wave, lane);
  else if (u == 2)  // U4T = g(U2T, U2)
    run_unit8(lds, s + (size_t)1 * SLOT, s + (size_t)10 * SLOT, s + (size_t)2 * SLOT, 1024, q, tid, wave, lane);
  else              // U4 = g(U2, U2T)
    run_unit8(lds, s + (size_t)10 * SLOT, s + (size_t)1 * SLOT, s + (size_t)11 * SLOT, 1024, q, tid, wave, lane);
}

// ---------------- k_big: F0[8192][1024] = XB_chunk4[8192x4096] * BTcat^T ----
// blocks 0..63: U8T/U8 squares (8ph units); 64..319: main (XCD-chunked)
__global__ __launch_bounds__(512) void k_big(
    const short* __restrict__ XB, const short* __restrict__ BTcat,
    short* __restrict__ FA, short* slab) {
  __shared__ __align__(16) char lds[131072];
  int tid = threadIdx.x, wave = tid >> 6, lane = tid & 63;
  int b = blockIdx.x;
  short* s = slab;
  if (b < 64) {
    int q = b & 31;
    if (b < 32)  // U8T = g(U4T, U4)
      run_unit8(lds, s + (size_t)2 * SLOT, s + (size_t)11 * SLOT, s + (size_t)3 * SLOT, 1024, q, tid, wave, lane);
    else         // U8 = g(U4, U4T)
      run_unit8(lds, s + (size_t)11 * SLOT, s + (size_t)2 * SLOT, s + (size_t)12 * SLOT, 1024, q, tid, wave, lane);
  } else {
    int c = b - 64;
    int c2 = (c & 7) * 32 + (c >> 3);          // bijective XCD chunking (256%8==0)
    f32x4 acc[4][4] = {};
    int row0 = (c2 >> 3) * 256, col0 = (c2 & 7) * 128;  // col-fastest: L2 A-reuse
    gemm8ph<3>(lds, acc, XB, 1024, BTcat, 4096, row0, col0, 64, tid, wave, lane);
    epi128<0, 0>(acc, FA, 1024, nullptr, row0, col0, 8192, wave, lane);
  }
}

// ---------------- tree level (UNCHANGED r9): combine + 0-2 square units -----
template<int OUT>
__global__ __launch_bounds__(256) void k_lvl(
    const short* __restrict__ Fin, const short* __restrict__ PT,
    void* __restrict__ Fout, int M, int nComb,
    const short* __restrict__ sA0, const short* __restrict__ sB0, short* __restrict__ sC0,
    const short* __restrict__ sA1, const short* __restrict__ sB1, short* __restrict__ sC1) {
  __shared__ __align__(16) char lds[65536];
  int tid = threadIdx.x, wave = tid >> 6, lane = tid & 63;
  int b = blockIdx.x;
  if (b < nComb) {
    f32x4 acc[4][4] = {};
    int row0 = (b >> 3) * 128, col0 = (b & 7) * 128;
    gemm128_d3<2>(lds, acc, Fin, 1024, PT, 1024, row0, col0, 32, tid, wave, lane);
    epi128<2, OUT>(acc, Fout, 1024, Fin, row0, col0, M, wave, lane);
  } else {
    int q = b - nComb;
    const short* sa = (q < 64) ? sA0 : sA1;
    const short* sb = (q < 64) ? sB0 : sB1;
    short* sc = (q < 64) ? sC0 : sC1;
    run_unit_d3(lds, sa, sb, sc, 1024, q & 63, tid, wave, lane);
  }
}

extern "C" void kernel_launch(void* const* d_in, const int* in_sizes, int n_in,
                              void* d_out, int out_size, void* d_ws, size_t ws_size,
                              hipStream_t stream) {
  const float* X = (const float*)d_in[0];   // [64,512,1024] fp32
  const float* W = (const float*)d_in[1];   // [1024,1024] fp32
  const float* U = (const float*)d_in[2];   // [1024,1024] fp32
  float* outp = (float*)d_out;              // [64,1024] fp32

  char* ws = (char*)d_ws;
  short* XB    = (short*)ws;                          // [0,64MB) bf16 X
  short* FB    = (short*)ws;                          // aliases XB (dead after k_big)
  short* BTcat = (short*)(ws + ((size_t)64 << 20));   // [64,72) bf16 [1024][4096]
  short* slab  = (short*)(ws + ((size_t)72 << 20));   // [72,108) 18 x 2MB slots
  short* FA    = (short*)(ws + ((size_t)108 << 20));  // [108,124) bf16 [8192][1024]
  auto sl = [&](int i) { return slab + (size_t)i * SLOT; };

  k_prep<<<7168, 256, 0, stream>>>(W, U, X, BTcat, slab, XB);
  k_pre1<<<128, 512, 0, stream>>>(slab, BTcat);
  k_pre2<<<128, 512, 0, stream>>>(slab, BTcat);
  k_big<<<320, 512, 0, stream>>>(XB, BTcat, FA, slab);

  // ph0: M=4096 (P=U4T); sq U16T=g(U8T,U8), U16=g(U8,U8T)
  k_lvl<0><<<384, 256, 0, stream>>>(FA, sl(2), FB, 4096, 256,
                                    sl(3), sl(12), sl(4), sl(12), sl(3), sl(13));
  // ph1: M=2048 (P=U8T); sq U32T, U32
  k_lvl<0><<<256, 256, 0, stream>>>(FB, sl(3), FA, 2048, 128,
                                    sl(4), sl(13), sl(5), sl(13), sl(4), sl(14));
  // ph2: M=1024 (P=U16T); sq U64T, U64
  k_lvl<0><<<192, 256, 0, stream>>>(FA, sl(4), FB, 1024, 64,
                                    sl(5), sl(14), sl(6), sl(14), sl(5), sl(15));
  // ph3: M=512 (P=U32T); sq U128T, U128 (U128 -> slot16, WU1 dead)
  k_lvl<0><<<160, 256, 0, stream>>>(FB, sl(5), FA, 512, 32,
                                    sl(6), sl(15), sl(7), sl(15), sl(6), sl(16));
  // ph4: M=256 (P=U64T); sq U256T only
  k_lvl<0><<<80, 256, 0, stream>>>(FA, sl(6), FB, 256, 16,
                                   sl(7), sl(16), sl(8), nullptr, nullptr, nullptr);
  // ph5: M=128 (P=U128T)
  k_lvl<0><<<8, 256, 0, stream>>>(FB, sl(7), FA, 128, 8,
                                  nullptr, nullptr, nullptr, nullptr, nullptr, nullptr);
  // ph6: M=64 (P=U256T), fp32 -> d_out
  k_lvl<1><<<8, 256, 0, stream>>>(FA, sl(8), outp, 64, 8,
                                  nullptr, nullptr, nullptr, nullptr, nullptr, nullptr);
}

// Round 11
// 319.994 us; speedup vs baseline: 2.0642x; 1.0224x over previous
//
#include <hip/hip_runtime.h>
#include <hip/hip_bf16.h>

typedef __attribute__((ext_vector_type(4))) float f32x4;
typedef __attribute__((ext_vector_type(8))) short bf16x8;
typedef __attribute__((ext_vector_type(4))) short s16x4;

#define SLOT (1024 * 1024)   // elements per 2MB bf16 power slot

__device__ __forceinline__ short f2bfs(float f) {
  __hip_bfloat16 h = __float2bfloat16(f);   // RNE
  union { __hip_bfloat16 h; short s; } u; u.h = h;
  return u.s;
}
__device__ __forceinline__ float bf2fs(short s) {
  union { unsigned u; float f; } v; v.u = ((unsigned)(unsigned short)s) << 16;
  return v.f;
}

// async global->LDS, 16B/lane; LDS dest linear (wave base + lane*16)
__device__ __forceinline__ void gload16(void* l, const void* g) {
  __builtin_amdgcn_global_load_lds(
      (const __attribute__((address_space(1))) unsigned int*)g,
      (__attribute__((address_space(3))) unsigned int*)l, 16, 0, 0);
}

// RM=0 identity; RM=2 seg-major radix-2: mul=((R>>6)<<7)|(R&63)
// RM=3 C=4 chunk view of XB: row=(R&63)*512 + (R>>6)*4 (K-blocks = next rows)
template<int RM>
__device__ __forceinline__ int rmap(int R) {
  return (RM == 0) ? R
       : (RM == 3) ? (((R & 63) << 9) | ((R >> 6) << 2))
                   : (((R >> 6) << 7) | (R & 63));
}

// ===========================================================================
// epilogue (shared): C/D layout col=lane&15, row=(lane>>4)*4+reg [HW-verified]
// waves decompose wm=wave>>1, wn=wave&1 (works for 4 or 8 waves).
// ADD: 0 none; 2 seg add (row+64, bf16). OUT: 0 bf16; 1 fp32
// ===========================================================================
template<int ADD, int OUT>
__device__ __forceinline__ void epi128(
    f32x4 (&acc)[4][4], void* __restrict__ Cp, int ldc,
    const short* __restrict__ AddP,
    int row0, int col0, int M, int wave, int lane) {
  const int wm = wave >> 1, wn = wave & 1;
  const int l16 = lane & 15;
  #pragma unroll
  for (int m = 0; m < 4; ++m) {
    #pragma unroll
    for (int n = 0; n < 4; ++n) {
      const int grow0 = row0 + wm * 64 + m * 16 + ((lane >> 4) << 2);
      const int gcol  = col0 + wn * 64 + n * 16 + l16;
      #pragma unroll
      for (int r = 0; r < 4; ++r) {
        const int R = grow0 + r;
        if (R < M) {
          float val = acc[m][n][r];
          if (ADD == 2) {
            int ar = (((R >> 6) << 7) | (R & 63)) + 64;
            val += bf2fs(AddP[(size_t)ar * 1024 + gcol]);
          }
          if (OUT == 0) ((short*)Cp)[(size_t)R * ldc + gcol] = f2bfs(val);
          else          ((float*)Cp)[(size_t)R * ldc + gcol] = val;
        }
      }
    }
  }
}

// ===========================================================================
// d4 core: 128x128 tile, 256 thr, 4 waves 2x2. Depth-4 counted-vmcnt pipeline:
// 5 LDS buffers (80KB -> exactly 2 blocks/CU), prologue 4 tiles, stage t+4,
// wait vmcnt(min(12, 4*(nkt-1-t))) -> tile t landed, 3 tiles stay in flight.
// ===========================================================================
struct TileAddr {
  const short *a0, *a1, *b0, *b1;
  int dA0, dA1, dB0, dB1;
  int offA[4], offB[4];
};
template<int RM>
__device__ __forceinline__ TileAddr mk_addr(
    const short* A, int lda, const short* BT, int ldb,
    int row0, int col0, int tid, int wave, int lane) {
  TileAddr t;
  const int wm = wave >> 1, wn = wave & 1;
  const int l16 = lane & 15, kg = lane >> 4;
  const int r0 = tid >> 2, g0 = tid & 3;
  const int gs0 = g0 ^ ((r0 >> 1) & 3);
  const int r1 = r0 + 64;
  const int gs1 = g0 ^ ((r1 >> 1) & 3);
  t.a0 = A + (size_t)rmap<RM>(row0 + r0) * lda + gs0 * 8;
  t.a1 = A + (size_t)rmap<RM>(row0 + r1) * lda + gs1 * 8;
  t.b0 = BT + (size_t)(col0 + r0) * ldb + gs0 * 8;
  t.b1 = BT + (size_t)(col0 + r1) * ldb + gs1 * 8;
  t.dA0 = tid * 16; t.dA1 = t.dA0 + 4096;
  t.dB0 = 8192 + tid * 16; t.dB1 = t.dB0 + 4096;
  #pragma unroll
  for (int m = 0; m < 4; ++m) {
    int row = wm * 64 + m * 16 + l16;
    t.offA[m] = (row * 4 + (kg ^ ((row >> 1) & 3))) * 16;
  }
  #pragma unroll
  for (int n = 0; n < 4; ++n) {
    int c = wn * 64 + n * 16 + l16;
    t.offB[n] = 8192 + (c * 4 + (kg ^ ((c >> 1) & 3))) * 16;
  }
  return t;
}
__device__ __forceinline__ void stage_to(const TileAddr& ta, char* buf, int ko) {
  gload16(buf + ta.dA0, ta.a0 + ko); gload16(buf + ta.dA1, ta.a1 + ko);
  gload16(buf + ta.dB0, ta.b0 + ko); gload16(buf + ta.dB1, ta.b1 + ko);
}
__device__ __forceinline__ void compute_step(
    const TileAddr& ta, const char* buf, f32x4 (&acc)[4][4]) {
  bf16x8 af[4], bfr[4];
  #pragma unroll
  for (int m = 0; m < 4; ++m) af[m] = *(const bf16x8*)(buf + ta.offA[m]);
  #pragma unroll
  for (int n = 0; n < 4; ++n) bfr[n] = *(const bf16x8*)(buf + ta.offB[n]);
  __builtin_amdgcn_s_setprio(1);
  #pragma unroll
  for (int m = 0; m < 4; ++m)
    #pragma unroll
    for (int n = 0; n < 4; ++n)
      acc[m][n] = __builtin_amdgcn_mfma_f32_16x16x32_bf16(af[m], bfr[n], acc[m][n], 0, 0, 0);
  __builtin_amdgcn_s_setprio(0);
}
template<int RM>
__device__ __forceinline__ void gemm128_d4(
    char* lds, f32x4 (&acc)[4][4],
    const short* __restrict__ A, int lda,
    const short* __restrict__ BT, int ldb,
    int row0, int col0, int nkt, int tid, int wave, int lane) {
  TileAddr ta = mk_addr<RM>(A, lda, BT, ldb, row0, col0, tid, wave, lane);
  #pragma unroll
  for (int p = 0; p < 4; ++p)
    stage_to(ta, lds + p * 16384, p * 32);
  int bufc = 0, bufn = 4;   // buf index of tile t, and of tile t+4 (mod 5)
  for (int t = 0; t < nkt; ++t) {
    const int w = nkt - 1 - t;
    if (w >= 3)      { asm volatile("s_waitcnt vmcnt(12)" ::: "memory"); }
    else if (w == 2) { asm volatile("s_waitcnt vmcnt(8)" ::: "memory"); }
    else if (w == 1) { asm volatile("s_waitcnt vmcnt(4)" ::: "memory"); }
    else             { asm volatile("s_waitcnt vmcnt(0)" ::: "memory"); }
    __builtin_amdgcn_s_barrier();
    asm volatile("" ::: "memory");
    if (t + 4 < nkt) stage_to(ta, lds + bufn * 16384, (t + 4) * 32);
    compute_step(ta, lds + bufc * 16384, acc);
    bufc = (bufc == 4) ? 0 : bufc + 1;
    bufn = (bufn == 4) ? 0 : bufn + 1;
  }
}
__device__ __forceinline__ void run_unit_d4(char* lds,
    const short* A, const short* BT, short* C, int ldc,
    int tile, int tid, int wave, int lane) {
  f32x4 acc[4][4] = {};
  int row0 = (tile >> 3) * 128, col0 = (tile & 7) * 128;
  gemm128_d4<0>(lds, acc, A, 1024, BT, 1024, row0, col0, 32, tid, wave, lane);
  epi128<0, 0>(acc, C, ldc, nullptr, row0, col0, 1024, wave, lane);
}

// ===========================================================================
// 8ph core (proven r10): 256x128 tile, 512 thr, 8 waves 4x2 (64x64/wave).
// BK=64; 2 fine phases per K-tile; A triple-buffered, B double-buffered;
// vmcnt(6) at Q0 (6 newest = SA(kt+1)+SB(kt+1)); vmcnt(0) final tile.
// LDS: A 3x32KB [0,98304) + B 2x16KB [98304,131072).
// ===========================================================================
template<int RM>
__device__ __forceinline__ void gemm8ph(
    char* lds, f32x4 (&acc)[4][4],
    const short* __restrict__ A, int lda,
    const short* __restrict__ BT, int ldb,
    int row0, int col0, int nkt, int tid, int wave, int lane) {
  const int wm = wave >> 1, wn = wave & 1;
  const int l16 = lane & 15, kg = (lane >> 4) & 3;

  const short* aP[2][2];
  #pragma unroll
  for (int l = 0; l < 2; ++l) {
    int G = l * 512 + tid;
    int rp = G >> 3, gs = (G & 7) ^ (rp & 7);
    #pragma unroll
    for (int h = 0; h < 2; ++h)
      aP[l][h] = A + (size_t)rmap<RM>(row0 + h * 128 + rp) * lda + gs * 8;
  }
  const short* bP[2];
  {
    int rp = tid >> 3, gs = (tid & 7) ^ (rp & 7);
    #pragma unroll
    for (int h = 0; h < 2; ++h)
      bP[h] = BT + (size_t)(col0 + h * 64 + rp) * ldb + gs * 8;
  }

  int offA[4][2], offB[4][2];
  #pragma unroll
  for (int m = 0; m < 4; ++m) {
    int rp = (wm & 1) * 64 + m * 16 + l16;
    #pragma unroll
    for (int ks = 0; ks < 2; ++ks) {
      int gsrc = ks * 4 + kg;
      offA[m][ks] = (wm >> 1) * 16384 + (rp * 8 + (gsrc ^ (rp & 7))) * 16;
    }
  }
  #pragma unroll
  for (int n = 0; n < 4; ++n) {
    int rp = n * 16 + l16;
    #pragma unroll
    for (int ks = 0; ks < 2; ++ks) {
      int gsrc = ks * 4 + kg;
      offB[n][ks] = wn * 8192 + (rp * 8 + (gsrc ^ (rp & 7))) * 16;
    }
  }

  auto SA = [&](int kt, int ad_t, int h) {
    char* dst = lds + ad_t * 32768 + h * 16384 + tid * 16;
    gload16(dst,        aP[0][h] + kt * 64);
    gload16(dst + 8192, aP[1][h] + kt * 64);
  };
  auto SB = [&](int kt, int h) {
    gload16(lds + 98304 + (kt & 1) * 16384 + h * 8192 + tid * 16,
            bP[h] + kt * 64);
  };

  SA(0, 0, 0); SA(0, 0, 1);
  SB(0, 0); SB(0, 1);
  SA(1, 1, 0); SA(1, 1, 1);
  SB(1, 0); SB(1, 1);

  bf16x8 bR[4][2];
  int ad = 0;
  for (int kt = 0; kt < nkt; ++kt) {
    char* baseA = lds + ad * 32768;
    char* baseB = lds + 98304 + (kt & 1) * 16384;
    const int ad2 = (ad >= 1) ? ad - 1 : 2;
    // ---------------- phase Q0 ----------------
    if (kt == nkt - 1) { asm volatile("s_waitcnt vmcnt(0)" ::: "memory"); }
    else               { asm volatile("s_waitcnt vmcnt(6)" ::: "memory"); }
    __builtin_amdgcn_s_barrier();
    __builtin_amdgcn_sched_barrier(0);
    {
      #pragma unroll
      for (int n = 0; n < 4; ++n)
        #pragma unroll
        for (int ks = 0; ks < 2; ++ks)
          bR[n][ks] = *(const bf16x8*)(baseB + offB[n][ks]);
      bf16x8 aR[2][2];
      #pragma unroll
      for (int mm = 0; mm < 2; ++mm)
        #pragma unroll
        for (int ks = 0; ks < 2; ++ks)
          aR[mm][ks] = *(const bf16x8*)(baseA + offA[mm][ks]);
      if (kt + 2 < nkt) { SA(kt + 2, ad2, 0); SA(kt + 2, ad2, 1); }
      __builtin_amdgcn_s_setprio(1);
      #pragma unroll
      for (int mm = 0; mm < 2; ++mm)
        #pragma unroll
        for (int n = 0; n < 4; ++n)
          #pragma unroll
          for (int ks = 0; ks < 2; ++ks)
            acc[mm][n] = __builtin_amdgcn_mfma_f32_16x16x32_bf16(
                aR[mm][ks], bR[n][ks], acc[mm][n], 0, 0, 0);
      __builtin_amdgcn_s_setprio(0);
    }
    // ---------------- phase Q1 ----------------
    __builtin_amdgcn_s_barrier();
    __builtin_amdgcn_sched_barrier(0);
    {
      bf16x8 aR[2][2];
      #pragma unroll
      for (int mm = 0; mm < 2; ++mm)
        #pragma unroll
        for (int ks = 0; ks < 2; ++ks)
          aR[mm][ks] = *(const bf16x8*)(baseA + offA[2 + mm][ks]);
      if (kt + 2 < nkt) { SB(kt + 2, 0); SB(kt + 2, 1); }
      __builtin_amdgcn_s_setprio(1);
      #pragma unroll
      for (int mm = 0; mm < 2; ++mm)
        #pragma unroll
        for (int n = 0; n < 4; ++n)
          #pragma unroll
          for (int ks = 0; ks < 2; ++ks)
            acc[2 + mm][n] = __builtin_amdgcn_mfma_f32_16x16x32_bf16(
                aR[mm][ks], bR[n][ks], acc[2 + mm][n], 0, 0, 0);
      __builtin_amdgcn_s_setprio(0);
    }
    ad = (ad == 2) ? 0 : ad + 1;
  }
}

__device__ __forceinline__ void run_unit8(char* lds,
    const short* A, const short* BT, short* C, int ldc,
    int tile, int tid, int wave, int lane) {
  f32x4 acc[4][4] = {};
  int row0 = (tile >> 3) * 256, col0 = (tile & 7) * 128;
  gemm8ph<0>(lds, acc, A, 1024, BT, 1024, row0, col0, 16, tid, wave, lane);
  epi128<0, 0>(acc, C, ldc, nullptr, row0, col0, 1024, wave, lane);
}

// Slots: 0 UT, 1 U2T, 2 U4T, 3 U8T, 4 U16T, 5 U32T, 6 U64T, 7 U128T, 8 U256T,
//        9 Ub, 10 U2, 11 U4, 12 U8, 13 U16, 14 U32, 15 U64, 16 WU1/U128, 17 Wb

// ---------------- k_prep: transposes + bf16 casts (incl. X) ----------------
__global__ __launch_bounds__(256) void k_prep(
    const float* __restrict__ W, const float* __restrict__ Uf,
    const float* __restrict__ X,
    short* __restrict__ BTcat, short* __restrict__ slab, short* __restrict__ XB) {
  __shared__ float tf[32][36];
  int b = blockIdx.x, t = threadIdx.x;
  if (b < 2048) {
    const float* src = (b < 1024) ? W : Uf;
    int bb = b & 1023;
    int i0 = (bb >> 5) * 32, j0 = (bb & 31) * 32;
    int r = t >> 3, c = (t & 7) * 4;
    *(f32x4*)&tf[r][c] = *(const f32x4*)(src + (size_t)(i0 + r) * 1024 + j0 + c);
    __syncthreads();
    s16x4 o;
    o.x = f2bfs(tf[c + 0][r]); o.y = f2bfs(tf[c + 1][r]);
    o.z = f2bfs(tf[c + 2][r]); o.w = f2bfs(tf[c + 3][r]);
    if (b < 1024)  // W^T -> BTcat col-block 3 (K idx 3072..4095)
      *(s16x4*)(BTcat + (size_t)(j0 + r) * 4096 + 3072 + i0 + c) = o;
    else           // U^T -> slot 0
      *(s16x4*)(slab + (size_t)(j0 + r) * 1024 + i0 + c) = o;
  } else if (b < 3072) {
    int q = b - 2048;   // first 512 = U cast (slot 9), next 512 = W cast (17)
    const float* src = (q < 512) ? Uf : W;
    short* dst = slab + (size_t)((q < 512) ? 9 : 17) * SLOT;
    int qq = q & 511;
    size_t base = (size_t)qq * 2048 + (size_t)t * 8;
    f32x4 a = *(const f32x4*)(src + base);
    f32x4 c2 = *(const f32x4*)(src + base + 4);
    bf16x8 o;
    o[0] = f2bfs(a.x);  o[1] = f2bfs(a.y);  o[2] = f2bfs(a.z);  o[3] = f2bfs(a.w);
    o[4] = f2bfs(c2.x); o[5] = f2bfs(c2.y); o[6] = f2bfs(c2.z); o[7] = f2bfs(c2.w);
    *(bf16x8*)(dst + base) = o;
  } else {
    int q = b - 3072;   // 0..4095: X cast
    size_t base = ((size_t)q * 256 + t) * 32;
    #pragma unroll
    for (int i = 0; i < 4; ++i) {
      f32x4 a = *(const f32x4*)(X + base + i * 8);
      f32x4 c2 = *(const f32x4*)(X + base + i * 8 + 4);
      bf16x8 o;
      o[0] = f2bfs(a.x);  o[1] = f2bfs(a.y);  o[2] = f2bfs(a.z);  o[3] = f2bfs(a.w);
      o[4] = f2bfs(c2.x); o[5] = f2bfs(c2.y); o[6] = f2bfs(c2.z); o[7] = f2bfs(c2.w);
      *(bf16x8*)(XB + base + i * 8) = o;
    }
  }
}

// ---------------- k_pre1: U2T, U2, TW1T -> BTcat blk2, WU1 (8ph units) ------
__global__ __launch_bounds__(512) void k_pre1(short* slab, short* BTcat) {
  __shared__ __align__(16) char lds[131072];
  int tid = threadIdx.x, wave = tid >> 6, lane = tid & 63;
  int b = blockIdx.x, u = b >> 5, q = b & 31;
  short* s = slab;
  if (u == 0)       // U2T = g(UT, Ub)
    run_unit8(lds, s, s + (size_t)9 * SLOT, s + (size_t)1 * SLOT, 1024, q, tid, wave, lane);
  else if (u == 1)  // U2 = g(Ub, UT)
    run_unit8(lds, s + (size_t)9 * SLOT, s, s + (size_t)10 * SLOT, 1024, q, tid, wave, lane);
  else if (u == 2)  // TW1T = g(UT, Wb) = (WU)^T
    run_unit8(lds, s, s + (size_t)17 * SLOT, BTcat + 2048, 4096, q, tid, wave, lane);
  else              // WU1 = g(Wb, UT) = W*U
    run_unit8(lds, s + (size_t)17 * SLOT, s, s + (size_t)16 * SLOT, 1024, q, tid, wave, lane);
}

// ---------------- k_pre2: TW2T, TW3T -> BTcat blk1/0; U4T, U4 (8ph) ---------
__global__ __launch_bounds__(512) void k_pre2(short* slab, short* BTcat) {
  __shared__ __align__(16) char lds[131072];
  int tid = threadIdx.x, wave = tid >> 6, lane = tid & 63;
  int b = blockIdx.x, u = b >> 5, q = b & 31;
  short* s = slab;
  if (u == 0)       // TW2T = g(U2T, Wb)
    run_unit8(lds, s + (size_t)1 * SLOT, s + (size_t)17 * SLOT, BTcat + 1024, 4096, q, tid, wave, lane);
  else if (u == 1)  // TW3T = g(U2T, WU1)
    run_unit8(lds, s + (size_t)1 * SLOT, s + (size_t)16 * SLOT, BTcat, 4096, q, tid, wave, lane);
  else if (u == 2)  // U4T = g(U2T, U2)
    run_unit8(lds, s + (size_t)1 * SLOT, s + (size_t)10 * SLOT, s + (size_t)2 * SLOT, 1024, q, tid, wave, lane);
  else              // U4 = g(U2, U2T)
    run_unit8(lds, s + (size_t)10 * SLOT, s + (size_t)1 * SLOT, s + (size_t)11 * SLOT, 1024, q, tid, wave, lane);
}

// ---------------- k_big: F0[8192][1024] = XB_chunk4[8192x4096] * BTcat^T ----
// PURE 256 blocks (no side units -> no stragglers at 1 block/CU)
__global__ __launch_bounds__(512) void k_big(
    const short* __restrict__ XB, const short* __restrict__ BTcat,
    short* __restrict__ FA) {
  __shared__ __align__(16) char lds[131072];
  int tid = threadIdx.x, wave = tid >> 6, lane = tid & 63;
  int c = blockIdx.x;
  int c2 = (c & 7) * 32 + (c >> 3);          // bijective XCD chunking (256%8==0)
  f32x4 acc[4][4] = {};
  int row0 = (c2 >> 3) * 256, col0 = (c2 & 7) * 128;  // col-fastest: L2 A-reuse
  gemm8ph<3>(lds, acc, XB, 1024, BTcat, 4096, row0, col0, 64, tid, wave, lane);
  epi128<0, 0>(acc, FA, 1024, nullptr, row0, col0, 8192, wave, lane);
}

// ---------------- tree level: combine (b < nComb) + 0-2 square units (d4) ---
// Power chain rides the tree: level k's sides build U^(2^(k+3)) needed at k+1.
template<int OUT>
__global__ __launch_bounds__(256) void k_lvl(
    const short* __restrict__ Fin, const short* __restrict__ PT,
    void* __restrict__ Fout, int M, int nComb,
    const short* __restrict__ sA0, const short* __restrict__ sB0, short* __restrict__ sC0,
    const short* __restrict__ sA1, const short* __restrict__ sB1, short* __restrict__ sC1) {
  __shared__ __align__(16) char lds[81920];
  int tid = threadIdx.x, wave = tid >> 6, lane = tid & 63;
  int b = blockIdx.x;
  if (b < nComb) {
    f32x4 acc[4][4] = {};
    int row0 = (b >> 3) * 128, col0 = (b & 7) * 128;
    gemm128_d4<2>(lds, acc, Fin, 1024, PT, 1024, row0, col0, 32, tid, wave, lane);
    epi128<2, OUT>(acc, Fout, 1024, Fin, row0, col0, M, wave, lane);
  } else {
    int q = b - nComb;
    const short* sa = (q < 64) ? sA0 : sA1;
    const short* sb = (q < 64) ? sB0 : sB1;
    short* sc = (q < 64) ? sC0 : sC1;
    run_unit_d4(lds, sa, sb, sc, 1024, q & 63, tid, wave, lane);
  }
}

extern "C" void kernel_launch(void* const* d_in, const int* in_sizes, int n_in,
                              void* d_out, int out_size, void* d_ws, size_t ws_size,
                              hipStream_t stream) {
  const float* X = (const float*)d_in[0];   // [64,512,1024] fp32
  const float* W = (const float*)d_in[1];   // [1024,1024] fp32
  const float* U = (const float*)d_in[2];   // [1024,1024] fp32
  float* outp = (float*)d_out;              // [64,1024] fp32

  char* ws = (char*)d_ws;
  short* XB    = (short*)ws;                          // [0,64MB) bf16 X
  short* FB    = (short*)ws;                          // aliases XB (dead after k_big)
  short* BTcat = (short*)(ws + ((size_t)64 << 20));   // [64,72) bf16 [1024][4096]
  short* slab  = (short*)(ws + ((size_t)72 << 20));   // [72,108) 18 x 2MB slots
  short* FA    = (short*)(ws + ((size_t)108 << 20));  // [108,124) bf16 [8192][1024]
  auto sl = [&](int i) { return slab + (size_t)i * SLOT; };

  k_prep<<<7168, 256, 0, stream>>>(W, U, X, BTcat, slab, XB);
  k_pre1<<<128, 512, 0, stream>>>(slab, BTcat);
  k_pre2<<<128, 512, 0, stream>>>(slab, BTcat);
  k_big<<<256, 512, 0, stream>>>(XB, BTcat, FA);

  // ph0: M=4096 (P=U4T); sides U8T=g(U4T,U4), U8=g(U4,U4T)
  k_lvl<0><<<384, 256, 0, stream>>>(FA, sl(2), FB, 4096, 256,
                                    sl(2), sl(11), sl(3), sl(11), sl(2), sl(12));
  // ph1: M=2048 (P=U8T); sides U16T=g(U8T,U8), U16=g(U8,U8T)
  k_lvl<0><<<256, 256, 0, stream>>>(FB, sl(3), FA, 2048, 128,
                                    sl(3), sl(12), sl(4), sl(12), sl(3), sl(13));
  // ph2: M=1024 (P=U16T); sides U32T, U32
  k_lvl<0><<<192, 256, 0, stream>>>(FA, sl(4), FB, 1024, 64,
                                    sl(4), sl(13), sl(5), sl(13), sl(4), sl(14));
  // ph3: M=512 (P=U32T); sides U64T, U64
  k_lvl<0><<<160, 256, 0, stream>>>(FB, sl(5), FA, 512, 32,
                                    sl(5), sl(14), sl(6), sl(14), sl(5), sl(15));
  // ph4: M=256 (P=U64T); sides U128T, U128 (U128 -> slot16, WU1 dead)
  k_lvl<0><<<144, 256, 0, stream>>>(FA, sl(6), FB, 256, 16,
                                    sl(6), sl(15), sl(7), sl(15), sl(6), sl(16));
  // ph5: M=128 (P=U128T); side U256T=g(U128T,U128)
  k_lvl<0><<<72, 256, 0, stream>>>(FB, sl(7), FA, 128, 8,
                                   sl(7), sl(16), sl(8), nullptr, nullptr, nullptr);
  // ph6: M=64 (P=U256T), fp32 -> d_out
  k_lvl<1><<<8, 256, 0, stream>>>(FA, sl(8), outp, 64, 8,
                                  nullptr, nullptr, nullptr, nullptr, nullptr, nullptr);
}

// Round 12
// 299.069 us; speedup vs baseline: 2.2086x; 1.0700x over previous
//
#include <hip/hip_runtime.h>
#include <hip/hip_bf16.h>

typedef __attribute__((ext_vector_type(4))) float f32x4;
typedef __attribute__((ext_vector_type(8))) short bf16x8;
typedef __attribute__((ext_vector_type(4))) short s16x4;

#define SLOT (1024 * 1024)   // elements per 2MB bf16 power slot

__device__ __forceinline__ short f2bfs(float f) {
  __hip_bfloat16 h = __float2bfloat16(f);   // RNE
  union { __hip_bfloat16 h; short s; } u; u.h = h;
  return u.s;
}
__device__ __forceinline__ float bf2fs(short s) {
  union { unsigned u; float f; } v; v.u = ((unsigned)(unsigned short)s) << 16;
  return v.f;
}

// async global->LDS, 16B/lane; LDS dest linear (wave base + lane*16)
__device__ __forceinline__ void gload16(void* l, const void* g) {
  __builtin_amdgcn_global_load_lds(
      (const __attribute__((address_space(1))) unsigned int*)g,
      (__attribute__((address_space(3))) unsigned int*)l, 16, 0, 0);
}

// RM=0 identity; RM=2 seg-major radix-2: mul=((R>>6)<<7)|(R&63)
// RM=3 C=4 chunk view of XB: row=(R&63)*512 + (R>>6)*4 (K-blocks = next rows)
template<int RM>
__device__ __forceinline__ int rmap(int R) {
  return (RM == 0) ? R
       : (RM == 3) ? (((R & 63) << 9) | ((R >> 6) << 2))
                   : (((R >> 6) << 7) | (R & 63));
}

// ===========================================================================
// epilogue (shared): C/D layout col=lane&15, row=(lane>>4)*4+reg [HW-verified]
// waves decompose wm=wave>>1, wn=wave&1 (works for 4 or 8 waves).
// ADD: 0 none; 2 seg add (row+64, bf16). OUT: 0 bf16; 1 fp32
// ===========================================================================
template<int ADD, int OUT>
__device__ __forceinline__ void epi128(
    f32x4 (&acc)[4][4], void* __restrict__ Cp, int ldc,
    const short* __restrict__ AddP,
    int row0, int col0, int M, int wave, int lane) {
  const int wm = wave >> 1, wn = wave & 1;
  const int l16 = lane & 15;
  #pragma unroll
  for (int m = 0; m < 4; ++m) {
    #pragma unroll
    for (int n = 0; n < 4; ++n) {
      const int grow0 = row0 + wm * 64 + m * 16 + ((lane >> 4) << 2);
      const int gcol  = col0 + wn * 64 + n * 16 + l16;
      #pragma unroll
      for (int r = 0; r < 4; ++r) {
        const int R = grow0 + r;
        if (R < M) {
          float val = acc[m][n][r];
          if (ADD == 2) {
            int ar = (((R >> 6) << 7) | (R & 63)) + 64;
            val += bf2fs(AddP[(size_t)ar * 1024 + gcol]);
          }
          if (OUT == 0) ((short*)Cp)[(size_t)R * ldc + gcol] = f2bfs(val);
          else          ((float*)Cp)[(size_t)R * ldc + gcol] = val;
        }
      }
    }
  }
}

// ===========================================================================
// d4 core: 128x128 tile, 256 thr, 4 waves 2x2. Depth-4 counted-vmcnt pipeline:
// 5 LDS buffers (80KB -> exactly 2 blocks/CU), prologue 4 tiles, stage t+4,
// wait vmcnt(min(12, 4*(nkt-1-t))) -> tile t landed, 3 tiles stay in flight.
// ===========================================================================
struct TileAddr {
  const short *a0, *a1, *b0, *b1;
  int dA0, dA1, dB0, dB1;
  int offA[4], offB[4];
};
template<int RM>
__device__ __forceinline__ TileAddr mk_addr(
    const short* A, int lda, const short* BT, int ldb,
    int row0, int col0, int tid, int wave, int lane) {
  TileAddr t;
  const int wm = wave >> 1, wn = wave & 1;
  const int l16 = lane & 15, kg = lane >> 4;
  const int r0 = tid >> 2, g0 = tid & 3;
  const int gs0 = g0 ^ ((r0 >> 1) & 3);
  const int r1 = r0 + 64;
  const int gs1 = g0 ^ ((r1 >> 1) & 3);
  t.a0 = A + (size_t)rmap<RM>(row0 + r0) * lda + gs0 * 8;
  t.a1 = A + (size_t)rmap<RM>(row0 + r1) * lda + gs1 * 8;
  t.b0 = BT + (size_t)(col0 + r0) * ldb + gs0 * 8;
  t.b1 = BT + (size_t)(col0 + r1) * ldb + gs1 * 8;
  t.dA0 = tid * 16; t.dA1 = t.dA0 + 4096;
  t.dB0 = 8192 + tid * 16; t.dB1 = t.dB0 + 4096;
  #pragma unroll
  for (int m = 0; m < 4; ++m) {
    int row = wm * 64 + m * 16 + l16;
    t.offA[m] = (row * 4 + (kg ^ ((row >> 1) & 3))) * 16;
  }
  #pragma unroll
  for (int n = 0; n < 4; ++n) {
    int c = wn * 64 + n * 16 + l16;
    t.offB[n] = 8192 + (c * 4 + (kg ^ ((c >> 1) & 3))) * 16;
  }
  return t;
}
__device__ __forceinline__ void stage_to(const TileAddr& ta, char* buf, int ko) {
  gload16(buf + ta.dA0, ta.a0 + ko); gload16(buf + ta.dA1, ta.a1 + ko);
  gload16(buf + ta.dB0, ta.b0 + ko); gload16(buf + ta.dB1, ta.b1 + ko);
}
__device__ __forceinline__ void compute_step(
    const TileAddr& ta, const char* buf, f32x4 (&acc)[4][4]) {
  bf16x8 af[4], bfr[4];
  #pragma unroll
  for (int m = 0; m < 4; ++m) af[m] = *(const bf16x8*)(buf + ta.offA[m]);
  #pragma unroll
  for (int n = 0; n < 4; ++n) bfr[n] = *(const bf16x8*)(buf + ta.offB[n]);
  __builtin_amdgcn_s_setprio(1);
  #pragma unroll
  for (int m = 0; m < 4; ++m)
    #pragma unroll
    for (int n = 0; n < 4; ++n)
      acc[m][n] = __builtin_amdgcn_mfma_f32_16x16x32_bf16(af[m], bfr[n], acc[m][n], 0, 0, 0);
  __builtin_amdgcn_s_setprio(0);
}
template<int RM>
__device__ __forceinline__ void gemm128_d4(
    char* lds, f32x4 (&acc)[4][4],
    const short* __restrict__ A, int lda,
    const short* __restrict__ BT, int ldb,
    int row0, int col0, int nkt, int tid, int wave, int lane) {
  TileAddr ta = mk_addr<RM>(A, lda, BT, ldb, row0, col0, tid, wave, lane);
  #pragma unroll
  for (int p = 0; p < 4; ++p)
    stage_to(ta, lds + p * 16384, p * 32);
  int bufc = 0, bufn = 4;   // buf index of tile t, and of tile t+4 (mod 5)
  for (int t = 0; t < nkt; ++t) {
    const int w = nkt - 1 - t;
    if (w >= 3)      { asm volatile("s_waitcnt vmcnt(12)" ::: "memory"); }
    else if (w == 2) { asm volatile("s_waitcnt vmcnt(8)" ::: "memory"); }
    else if (w == 1) { asm volatile("s_waitcnt vmcnt(4)" ::: "memory"); }
    else             { asm volatile("s_waitcnt vmcnt(0)" ::: "memory"); }
    __builtin_amdgcn_s_barrier();
    asm volatile("" ::: "memory");
    if (t + 4 < nkt) stage_to(ta, lds + bufn * 16384, (t + 4) * 32);
    compute_step(ta, lds + bufc * 16384, acc);
    bufc = (bufc == 4) ? 0 : bufc + 1;
    bufn = (bufn == 4) ? 0 : bufn + 1;
  }
}
__device__ __forceinline__ void run_unit_d4(char* lds,
    const short* A, const short* BT, short* C, int ldc,
    int tile, int tid, int wave, int lane) {
  f32x4 acc[4][4] = {};
  int row0 = (tile >> 3) * 128, col0 = (tile & 7) * 128;
  gemm128_d4<0>(lds, acc, A, 1024, BT, 1024, row0, col0, 32, tid, wave, lane);
  epi128<0, 0>(acc, C, ldc, nullptr, row0, col0, 1024, wave, lane);
}

// ===========================================================================
// 8ph core (proven r10/r11): 256x128 tile, 512 thr, 8 waves 4x2 (64x64/wave).
// BK=64; 2 fine phases per K-tile; A triple-buffered, B double-buffered;
// vmcnt(6) at Q0 (6 newest = SA(kt+1)+SB(kt+1)); vmcnt(0) final tile.
// LDS: A 3x32KB [0,98304) + B 2x16KB [98304,131072).
// ===========================================================================
template<int RM>
__device__ __forceinline__ void gemm8ph(
    char* lds, f32x4 (&acc)[4][4],
    const short* __restrict__ A, int lda,
    const short* __restrict__ BT, int ldb,
    int row0, int col0, int nkt, int tid, int wave, int lane) {
  const int wm = wave >> 1, wn = wave & 1;
  const int l16 = lane & 15, kg = (lane >> 4) & 3;

  const short* aP[2][2];
  #pragma unroll
  for (int l = 0; l < 2; ++l) {
    int G = l * 512 + tid;
    int rp = G >> 3, gs = (G & 7) ^ (rp & 7);
    #pragma unroll
    for (int h = 0; h < 2; ++h)
      aP[l][h] = A + (size_t)rmap<RM>(row0 + h * 128 + rp) * lda + gs * 8;
  }
  const short* bP[2];
  {
    int rp = tid >> 3, gs = (tid & 7) ^ (rp & 7);
    #pragma unroll
    for (int h = 0; h < 2; ++h)
      bP[h] = BT + (size_t)(col0 + h * 64 + rp) * ldb + gs * 8;
  }

  int offA[4][2], offB[4][2];
  #pragma unroll
  for (int m = 0; m < 4; ++m) {
    int rp = (wm & 1) * 64 + m * 16 + l16;
    #pragma unroll
    for (int ks = 0; ks < 2; ++ks) {
      int gsrc = ks * 4 + kg;
      offA[m][ks] = (wm >> 1) * 16384 + (rp * 8 + (gsrc ^ (rp & 7))) * 16;
    }
  }
  #pragma unroll
  for (int n = 0; n < 4; ++n) {
    int rp = n * 16 + l16;
    #pragma unroll
    for (int ks = 0; ks < 2; ++ks) {
      int gsrc = ks * 4 + kg;
      offB[n][ks] = wn * 8192 + (rp * 8 + (gsrc ^ (rp & 7))) * 16;
    }
  }

  auto SA = [&](int kt, int ad_t, int h) {
    char* dst = lds + ad_t * 32768 + h * 16384 + tid * 16;
    gload16(dst,        aP[0][h] + kt * 64);
    gload16(dst + 8192, aP[1][h] + kt * 64);
  };
  auto SB = [&](int kt, int h) {
    gload16(lds + 98304 + (kt & 1) * 16384 + h * 8192 + tid * 16,
            bP[h] + kt * 64);
  };

  SA(0, 0, 0); SA(0, 0, 1);
  SB(0, 0); SB(0, 1);
  SA(1, 1, 0); SA(1, 1, 1);
  SB(1, 0); SB(1, 1);

  bf16x8 bR[4][2];
  int ad = 0;
  for (int kt = 0; kt < nkt; ++kt) {
    char* baseA = lds + ad * 32768;
    char* baseB = lds + 98304 + (kt & 1) * 16384;
    const int ad2 = (ad >= 1) ? ad - 1 : 2;
    // ---------------- phase Q0 ----------------
    if (kt == nkt - 1) { asm volatile("s_waitcnt vmcnt(0)" ::: "memory"); }
    else               { asm volatile("s_waitcnt vmcnt(6)" ::: "memory"); }
    __builtin_amdgcn_s_barrier();
    __builtin_amdgcn_sched_barrier(0);
    {
      #pragma unroll
      for (int n = 0; n < 4; ++n)
        #pragma unroll
        for (int ks = 0; ks < 2; ++ks)
          bR[n][ks] = *(const bf16x8*)(baseB + offB[n][ks]);
      bf16x8 aR[2][2];
      #pragma unroll
      for (int mm = 0; mm < 2; ++mm)
        #pragma unroll
        for (int ks = 0; ks < 2; ++ks)
          aR[mm][ks] = *(const bf16x8*)(baseA + offA[mm][ks]);
      if (kt + 2 < nkt) { SA(kt + 2, ad2, 0); SA(kt + 2, ad2, 1); }
      __builtin_amdgcn_s_setprio(1);
      #pragma unroll
      for (int mm = 0; mm < 2; ++mm)
        #pragma unroll
        for (int n = 0; n < 4; ++n)
          #pragma unroll
          for (int ks = 0; ks < 2; ++ks)
            acc[mm][n] = __builtin_amdgcn_mfma_f32_16x16x32_bf16(
                aR[mm][ks], bR[n][ks], acc[mm][n], 0, 0, 0);
      __builtin_amdgcn_s_setprio(0);
    }
    // ---------------- phase Q1 ----------------
    __builtin_amdgcn_s_barrier();
    __builtin_amdgcn_sched_barrier(0);
    {
      bf16x8 aR[2][2];
      #pragma unroll
      for (int mm = 0; mm < 2; ++mm)
        #pragma unroll
        for (int ks = 0; ks < 2; ++ks)
          aR[mm][ks] = *(const bf16x8*)(baseA + offA[2 + mm][ks]);
      if (kt + 2 < nkt) { SB(kt + 2, 0); SB(kt + 2, 1); }
      __builtin_amdgcn_s_setprio(1);
      #pragma unroll
      for (int mm = 0; mm < 2; ++mm)
        #pragma unroll
        for (int n = 0; n < 4; ++n)
          #pragma unroll
          for (int ks = 0; ks < 2; ++ks)
            acc[2 + mm][n] = __builtin_amdgcn_mfma_f32_16x16x32_bf16(
                aR[mm][ks], bR[n][ks], acc[2 + mm][n], 0, 0, 0);
      __builtin_amdgcn_s_setprio(0);
    }
    ad = (ad == 2) ? 0 : ad + 1;
  }
}

__device__ __forceinline__ void run_unit8(char* lds,
    const short* A, const short* BT, short* C, int ldc,
    int tile, int tid, int wave, int lane) {
  f32x4 acc[4][4] = {};
  int row0 = (tile >> 3) * 256, col0 = (tile & 7) * 128;
  gemm8ph<0>(lds, acc, A, 1024, BT, 1024, row0, col0, 16, tid, wave, lane);
  epi128<0, 0>(acc, C, ldc, nullptr, row0, col0, 1024, wave, lane);
}

// Slots: 0 UT, 1 U2T, 2 U4T, 3 U8T, 4 U16T, 5 U32T, 6 U64T, 7 U128T, 8 U256T,
//        9 Ub, 10 U2, 11 U4, 12 U8, 13 U16, 14 U32, 15 U64, 16 WU1/U128, 17 Wb

// ---------------- k_prep_tc: transposes + U/W bf16 casts (no X) -------------
__global__ __launch_bounds__(256) void k_prep_tc(
    const float* __restrict__ W, const float* __restrict__ Uf,
    short* __restrict__ BTcat, short* __restrict__ slab) {
  __shared__ float tf[32][36];
  int b = blockIdx.x, t = threadIdx.x;
  if (b < 2048) {
    const float* src = (b < 1024) ? W : Uf;
    int bb = b & 1023;
    int i0 = (bb >> 5) * 32, j0 = (bb & 31) * 32;
    int r = t >> 3, c = (t & 7) * 4;
    *(f32x4*)&tf[r][c] = *(const f32x4*)(src + (size_t)(i0 + r) * 1024 + j0 + c);
    __syncthreads();
    s16x4 o;
    o.x = f2bfs(tf[c + 0][r]); o.y = f2bfs(tf[c + 1][r]);
    o.z = f2bfs(tf[c + 2][r]); o.w = f2bfs(tf[c + 3][r]);
    if (b < 1024)  // W^T -> BTcat col-block 3 (K idx 3072..4095)
      *(s16x4*)(BTcat + (size_t)(j0 + r) * 4096 + 3072 + i0 + c) = o;
    else           // U^T -> slot 0
      *(s16x4*)(slab + (size_t)(j0 + r) * 1024 + i0 + c) = o;
  } else {
    int q = b - 2048;   // first 512 = U cast (slot 9), next 512 = W cast (17)
    const float* src = (q < 512) ? Uf : W;
    short* dst = slab + (size_t)((q < 512) ? 9 : 17) * SLOT;
    int qq = q & 511;
    size_t base = (size_t)qq * 2048 + (size_t)t * 8;
    f32x4 a = *(const f32x4*)(src + base);
    f32x4 c2 = *(const f32x4*)(src + base + 4);
    bf16x8 o;
    o[0] = f2bfs(a.x);  o[1] = f2bfs(a.y);  o[2] = f2bfs(a.z);  o[3] = f2bfs(a.w);
    o[4] = f2bfs(c2.x); o[5] = f2bfs(c2.y); o[6] = f2bfs(c2.z); o[7] = f2bfs(c2.w);
    *(bf16x8*)(dst + base) = o;
  }
}

// ---------------- k_fuse<PH>: pre units (blocks 0-127) + X-cast half --------
// PH=0: pre1 units {U2T, U2, TW1T->BTcat blk2, WU1} + X floats [0, 16.7M)
// PH=1: pre2 units {TW2T, TW3T, U4T, U4}           + X floats [16.7M, 33.5M)
// X-cast COALESCED: lane reads f32x4 at tid*4 (1KB/wave), writes s16x4 (8B).
template<int PH>
__global__ __launch_bounds__(512) void k_fuse(
    const float* __restrict__ X, short* __restrict__ XB,
    short* slab, short* BTcat) {
  __shared__ __align__(16) char lds[131072];
  int tid = threadIdx.x;
  int b = blockIdx.x;
  short* s = slab;
  if (b < 128) {
    int wave = tid >> 6, lane = tid & 63;
    int u = b >> 5, q = b & 31;
    if (PH == 0) {
      if (u == 0)       // U2T = g(UT, Ub)
        run_unit8(lds, s, s + (size_t)9 * SLOT, s + (size_t)1 * SLOT, 1024, q, tid, wave, lane);
      else if (u == 1)  // U2 = g(Ub, UT)
        run_unit8(lds, s + (size_t)9 * SLOT, s, s + (size_t)10 * SLOT, 1024, q, tid, wave, lane);
      else if (u == 2)  // TW1T = g(UT, Wb) = (WU)^T -> BTcat blk2
        run_unit8(lds, s, s + (size_t)17 * SLOT, BTcat + 2048, 4096, q, tid, wave, lane);
      else              // WU1 = g(Wb, UT) = W*U
        run_unit8(lds, s + (size_t)17 * SLOT, s, s + (size_t)16 * SLOT, 1024, q, tid, wave, lane);
    } else {
      if (u == 0)       // TW2T = g(U2T, Wb)
        run_unit8(lds, s + (size_t)1 * SLOT, s + (size_t)17 * SLOT, BTcat + 1024, 4096, q, tid, wave, lane);
      else if (u == 1)  // TW3T = g(U2T, WU1)
        run_unit8(lds, s + (size_t)1 * SLOT, s + (size_t)16 * SLOT, BTcat, 4096, q, tid, wave, lane);
      else if (u == 2)  // U4T = g(U2T, U2)
        run_unit8(lds, s + (size_t)1 * SLOT, s + (size_t)10 * SLOT, s + (size_t)2 * SLOT, 1024, q, tid, wave, lane);
      else              // U4 = g(U2, U2T)
        run_unit8(lds, s + (size_t)10 * SLOT, s + (size_t)1 * SLOT, s + (size_t)11 * SLOT, 1024, q, tid, wave, lane);
    }
  } else {
    // X-cast: block handles 8192 consecutive floats, fully coalesced
    size_t base = ((size_t)(b - 128 + PH * 2048)) * 8192;
    #pragma unroll
    for (int i = 0; i < 4; ++i) {
      size_t idx = base + (size_t)i * 2048 + (size_t)tid * 4;
      f32x4 v = *(const f32x4*)(X + idx);
      s16x4 o;
      o.x = f2bfs(v.x); o.y = f2bfs(v.y); o.z = f2bfs(v.z); o.w = f2bfs(v.w);
      *(s16x4*)(XB + idx) = o;
    }
  }
}

// ---------------- k_big: F0[8192][1024] = XB_chunk4[8192x4096] * BTcat^T ----
// PURE 256 blocks (no side units -> no stragglers at 1 block/CU)
__global__ __launch_bounds__(512) void k_big(
    const short* __restrict__ XB, const short* __restrict__ BTcat,
    short* __restrict__ FA) {
  __shared__ __align__(16) char lds[131072];
  int tid = threadIdx.x, wave = tid >> 6, lane = tid & 63;
  int c = blockIdx.x;
  int c2 = (c & 7) * 32 + (c >> 3);          // bijective XCD chunking (256%8==0)
  f32x4 acc[4][4] = {};
  int row0 = (c2 >> 3) * 256, col0 = (c2 & 7) * 128;  // col-fastest: L2 A-reuse
  gemm8ph<3>(lds, acc, XB, 1024, BTcat, 4096, row0, col0, 64, tid, wave, lane);
  epi128<0, 0>(acc, FA, 1024, nullptr, row0, col0, 8192, wave, lane);
}

// ---------------- tree level: combine (b < nComb) + 0-2 square units (d4) ---
// Power chain rides the tree: level k's sides build U^(2^(k+3)) needed at k+1.
template<int OUT>
__global__ __launch_bounds__(256) void k_lvl(
    const short* __restrict__ Fin, const short* __restrict__ PT,
    void* __restrict__ Fout, int M, int nComb,
    const short* __restrict__ sA0, const short* __restrict__ sB0, short* __restrict__ sC0,
    const short* __restrict__ sA1, const short* __restrict__ sB1, short* __restrict__ sC1) {
  __shared__ __align__(16) char lds[81920];
  int tid = threadIdx.x, wave = tid >> 6, lane = tid & 63;
  int b = blockIdx.x;
  if (b < nComb) {
    f32x4 acc[4][4] = {};
    int row0 = (b >> 3) * 128, col0 = (b & 7) * 128;
    gemm128_d4<2>(lds, acc, Fin, 1024, PT, 1024, row0, col0, 32, tid, wave, lane);
    epi128<2, OUT>(acc, Fout, 1024, Fin, row0, col0, M, wave, lane);
  } else {
    int q = b - nComb;
    const short* sa = (q < 64) ? sA0 : sA1;
    const short* sb = (q < 64) ? sB0 : sB1;
    short* sc = (q < 64) ? sC0 : sC1;
    run_unit_d4(lds, sa, sb, sc, 1024, q & 63, tid, wave, lane);
  }
}

extern "C" void kernel_launch(void* const* d_in, const int* in_sizes, int n_in,
                              void* d_out, int out_size, void* d_ws, size_t ws_size,
                              hipStream_t stream) {
  const float* X = (const float*)d_in[0];   // [64,512,1024] fp32
  const float* W = (const float*)d_in[1];   // [1024,1024] fp32
  const float* U = (const float*)d_in[2];   // [1024,1024] fp32
  float* outp = (float*)d_out;              // [64,1024] fp32

  char* ws = (char*)d_ws;
  short* XB    = (short*)ws;                          // [0,64MB) bf16 X
  short* FB    = (short*)ws;                          // aliases XB (dead after k_big)
  short* BTcat = (short*)(ws + ((size_t)64 << 20));   // [64,72) bf16 [1024][4096]
  short* slab  = (short*)(ws + ((size_t)72 << 20));   // [72,108) 18 x 2MB slots
  short* FA    = (short*)(ws + ((size_t)108 << 20));  // [108,124) bf16 [8192][1024]
  auto sl = [&](int i) { return slab + (size_t)i * SLOT; };

  k_prep_tc<<<3072, 256, 0, stream>>>(W, U, BTcat, slab);
  k_fuse<0><<<2176, 512, 0, stream>>>(X, XB, slab, BTcat);   // pre1 + X-cast A
  k_fuse<1><<<2176, 512, 0, stream>>>(X, XB, slab, BTcat);   // pre2 + X-cast B
  k_big<<<256, 512, 0, stream>>>(XB, BTcat, FA);

  // ph0: M=4096 (P=U4T); sides U8T=g(U4T,U4), U8=g(U4,U4T)
  k_lvl<0><<<384, 256, 0, stream>>>(FA, sl(2), FB, 4096, 256,
                                    sl(2), sl(11), sl(3), sl(11), sl(2), sl(12));
  // ph1: M=2048 (P=U8T); sides U16T=g(U8T,U8), U16=g(U8,U8T)
  k_lvl<0><<<256, 256, 0, stream>>>(FB, sl(3), FA, 2048, 128,
                                    sl(3), sl(12), sl(4), sl(12), sl(3), sl(13));
  // ph2: M=1024 (P=U16T); sides U32T, U32
  k_lvl<0><<<192, 256, 0, stream>>>(FA, sl(4), FB, 1024, 64,
                                    sl(4), sl(13), sl(5), sl(13), sl(4), sl(14));
  // ph3: M=512 (P=U32T); sides U64T, U64
  k_lvl<0><<<160, 256, 0, stream>>>(FB, sl(5), FA, 512, 32,
                                    sl(5), sl(14), sl(6), sl(14), sl(5), sl(15));
  // ph4: M=256 (P=U64T); sides U128T, U128 (U128 -> slot16, WU1 dead)
  k_lvl<0><<<144, 256, 0, stream>>>(FA, sl(6), FB, 256, 16,
                                    sl(6), sl(15), sl(7), sl(15), sl(6), sl(16));
  // ph5: M=128 (P=U128T); side U256T=g(U128T,U128)
  k_lvl<0><<<72, 256, 0, stream>>>(FB, sl(7), FA, 128, 8,
                                   sl(7), sl(16), sl(8), nullptr, nullptr, nullptr);
  // ph6: M=64 (P=U256T), fp32 -> d_out
  k_lvl<1><<<8, 256, 0, stream>>>(FA, sl(8), outp, 64, 8,
                                  nullptr, nullptr, nullptr, nullptr, nullptr, nullptr);
}